// Round 15
// baseline (350.082 us; speedup 1.0000x reference)
//
#include <hip/hip_runtime.h>
#include <math.h>

#define BB 2
#define TT 1024
#define DD 1536
#define HH 12
#define TQK 768
#define TVv 1536
#define CQKV 3072
#define NQKVG 4608
#define EPSF 1e-6f
#define NBH (BB * HH)   // 24

typedef __attribute__((ext_vector_type(8))) _Float16 half8v;
typedef __attribute__((ext_vector_type(4))) float f32x4;

__device__ __forceinline__ float siluf(float x) { return x / (1.f + expf(-x)); }

__device__ __forceinline__ uint pk2h(float a, float b) {
  union { _Float16 h[2]; uint u; } p;
  p.h[0] = (_Float16)a; p.h[1] = (_Float16)b;
  return p.u;
}

// async global->LDS (GEMM staging)
__device__ __forceinline__ void gload16(const void* g, void* l) {
  __builtin_amdgcn_global_load_lds(
      (const __attribute__((address_space(1))) void*)g,
      (__attribute__((address_space(3))) void*)l, 16, 0, 0);
}

// ---------------------------------------------------------------------------
// fp16 MFMA GEMM (proven): C = X @ W^T -> f32.
// ---------------------------------------------------------------------------
__global__ __launch_bounds__(256) void gemm_f16(
    const ushort* __restrict__ X, const ushort* __restrict__ W,
    float* __restrict__ C1, float* __restrict__ C2,
    int M, int N, int K, int ldc1, int ldc2, int nsplit)
{
  __shared__ ushort Ah[128 * 64];
  __shared__ ushort Bh[128 * 64];
  const int tid  = threadIdx.x;
  const int lane = tid & 63;
  const int w    = tid >> 6;
  const int wr   = w >> 1, wc = w & 1;
  const int r0   = blockIdx.y * 128, c0 = blockIdx.x * 128;

  const int dr   = lane >> 3;
  const int slot = (lane & 7) ^ dr;

  f32x4 acc[4][4];
#pragma unroll
  for (int m = 0; m < 4; ++m)
#pragma unroll
    for (int n = 0; n < 4; ++n)
#pragma unroll
      for (int j = 0; j < 4; ++j) acc[m][n][j] = 0.f;

  for (int k0 = 0; k0 < K; k0 += 64) {
#pragma unroll
    for (int j = 0; j < 4; ++j) {
      const int row  = (w * 4 + j) * 8 + dr;
      const size_t xo = (size_t)(r0 + row) * K + k0 + slot * 8;
      const size_t wo = (size_t)(c0 + row) * K + k0 + slot * 8;
      const int ldso = (w * 4 + j) * 512;
      gload16(X + xo, Ah + ldso);
      gload16(W + wo, Bh + ldso);
    }
    __syncthreads();
#pragma unroll
    for (int kk = 0; kk < 2; ++kk) {
      const int kc8 = kk * 4 + (lane >> 4);
      const int sw  = (kc8 ^ (lane & 7)) << 3;
      half8v a[4], b[4];
#pragma unroll
      for (int m = 0; m < 4; ++m)
        a[m] = *(const half8v*)(Ah + (wr * 64 + m * 16 + (lane & 15)) * 64 + sw);
#pragma unroll
      for (int n = 0; n < 4; ++n)
        b[n] = *(const half8v*)(Bh + (wc * 64 + n * 16 + (lane & 15)) * 64 + sw);
#pragma unroll
      for (int m = 0; m < 4; ++m)
#pragma unroll
        for (int n = 0; n < 4; ++n)
          acc[m][n] = __builtin_amdgcn_mfma_f32_16x16x32_f16(a[m], b[n], acc[m][n], 0, 0, 0);
    }
    __syncthreads();
  }

  float* Cp; int ldc, cc0;
  if (c0 < nsplit) { Cp = C1; ldc = ldc1; cc0 = c0; }
  else             { Cp = C2; ldc = ldc2; cc0 = c0 - nsplit; }

  const int crow = (lane >> 4) * 4;
  const int ccol = lane & 15;
#pragma unroll
  for (int m = 0; m < 4; ++m)
#pragma unroll
    for (int j = 0; j < 4; ++j) {
      float* cp = Cp + (size_t)(r0 + wr * 64 + m * 16 + crow + j) * ldc + cc0 + wc * 64 + ccol;
#pragma unroll
      for (int n = 0; n < 4; ++n) cp[n * 16] = acc[m][n][j];
    }
}

// ---------------------------------------------------------------------------
// f32 -> fp16 casts.
// ---------------------------------------------------------------------------
__device__ __forceinline__ void cast8_store(const float* f, ushort* dst, size_t e)
{
  uint4 pk;
  pk.x = pk2h(f[0], f[1]); pk.y = pk2h(f[2], f[3]);
  pk.z = pk2h(f[4], f[5]); pk.w = pk2h(f[6], f[7]);
  *(uint4*)(dst + e) = pk;
}

__global__ void cast_f16_kernel(const float* __restrict__ src, ushort* __restrict__ dst)
{
  int cid = blockIdx.x * blockDim.x + threadIdx.x;
  size_t e = (size_t)cid * 8;
  float f[8];
  *(float4*)(f)     = *(const float4*)(src + e);
  *(float4*)(f + 4) = *(const float4*)(src + e + 4);
  cast8_store(f, dst, e);
}

__global__ void cast_w4_kernel(const float* __restrict__ wq, const float* __restrict__ wk,
                               const float* __restrict__ wv, const float* __restrict__ wg,
                               ushort* __restrict__ dst)
{
  int cid = blockIdx.x * blockDim.x + threadIdx.x;
  size_t e = (size_t)cid * 8;
  const float* src; size_t off;
  if (e < 1179648)      { src = wq; off = e; }
  else if (e < 2359296) { src = wk; off = e - 1179648; }
  else if (e < 4718592) { src = wv; off = e - 2359296; }
  else                  { src = wg; off = e - 4718592; }
  float f[8];
  *(float4*)(f)     = *(const float4*)(src + off);
  *(float4*)(f + 4) = *(const float4*)(src + off + 4);
  cast8_store(f, dst, e);
}

// ---------------------------------------------------------------------------
// Causal depthwise conv (K=4) + SiLU + fused L2-norm (q,k heads).
// ---------------------------------------------------------------------------
__global__ void conv_silu_kernel(
    const float* __restrict__ pre,
    const float* __restrict__ qw, const float* __restrict__ kw, const float* __restrict__ vw,
    float* __restrict__ qc, float* __restrict__ kc, float* __restrict__ vc)
{
  int idx = blockIdx.x * blockDim.x + threadIdx.x;
  int c  = idx % CQKV;
  int bt = idx / CQKV;
  int t  = bt % TT;
  int b  = bt / TT;

  const float* wp;
  if (c < TQK)          wp = qw + (size_t)c * 4;
  else if (c < 2 * TQK) wp = kw + (size_t)(c - TQK) * 4;
  else                  wp = vw + (size_t)(c - 2 * TQK) * 4;

  float s = 0.f;
#pragma unroll
  for (int j = 0; j < 4; ++j) {
    int ts = t - 3 + j;
    if (ts >= 0) s = fmaf(pre[(size_t)(b * TT + ts) * CQKV + c], wp[j], s);
  }
  s = siluf(s);

  if (c < 2 * TQK) {
    float ss = s * s;
#pragma unroll
    for (int m = 32; m >= 1; m >>= 1) ss += __shfl_xor(ss, m, 64);
    s = s / fmaxf(sqrtf(ss), EPSF);
  }

  if (c < TQK) {
    int h = c >> 6, d = c & 63;
    qc[((size_t)(b * HH + h) * TT + t) * 64 + d] = s;
  } else if (c < 2 * TQK) {
    int c2 = c - TQK; int h = c2 >> 6, d = c2 & 63;
    kc[((size_t)(b * HH + h) * TT + t) * 64 + d] = s;
  } else {
    int c2 = c - 2 * TQK; int h = c2 >> 7, d = c2 & 127;
    vc[((size_t)(b * HH + h) * TT + t) * 128 + d] = s;
  }
}

// ---------------------------------------------------------------------------
// Gating: block per row; writes interleaved (alpha,beta).
// ---------------------------------------------------------------------------
__global__ __launch_bounds__(256) void gate_kernel(
    const float* __restrict__ x, const float* __restrict__ w_a, const float* __restrict__ w_b,
    const float* __restrict__ A_log, const float* __restrict__ dt_bias,
    float* __restrict__ abi)
{
  const int m    = blockIdx.x;
  const int w    = threadIdx.x >> 6;
  const int lane = threadIdx.x & 63;
  const float* xr = x + (size_t)m * DD;
  float xv[24];
#pragma unroll
  for (int i = 0; i < 24; ++i) xv[i] = xr[lane + i * 64];
  const int b = m / TT, t = m % TT;
#pragma unroll
  for (int j = 0; j < 6; ++j) {
    int o = w * 6 + j;
    bool isA = o < HH;
    int h = isA ? o : o - HH;
    const float* wr = (isA ? w_a : w_b) + (size_t)h * DD;
    float s = 0.f;
#pragma unroll
    for (int i = 0; i < 24; ++i) s = fmaf(xv[i], wr[lane + i * 64], s);
#pragma unroll
    for (int mm = 32; mm >= 1; mm >>= 1) s += __shfl_xor(s, mm, 64);
    if (lane == 0) {
      size_t idx = ((size_t)(b * HH + h) * TT + t) * 2;
      if (isA) {
        float a  = s + dt_bias[h];
        float sp = (a > 20.f) ? a : log1pf(expf(a));
        abi[idx] = expf(-expf(A_log[h]) * sp);
      } else {
        abi[idx + 1] = 2.f / (1.f + expf(-s));
      }
    }
  }
}

// ---------------------------------------------------------------------------
// CHUNKED gated delta rule (WY form), C=64 steps/chunk, 16 serial chunks.
// R14 + fix: removed the tmpf[1056] OOB write (stomped g_s[0] -> ph8's
// P[:,0] used e^{g_row-0} instead of e^{g_row-g_0} -> absmax 0.605).
// ---------------------------------------------------------------------------
__device__ __forceinline__ void gemm64(
    const _Float16* XB, int xstr, const _Float16* YB, int ystr,
    int wr, int wc, int lane, int ksteps, int kpad, f32x4 acc[2][2])
{
#pragma unroll
  for (int m = 0; m < 2; ++m)
#pragma unroll
    for (int n = 0; n < 2; ++n)
#pragma unroll
      for (int j = 0; j < 4; ++j) acc[m][n][j] = 0.f;
#pragma unroll 4
  for (int kk = 0; kk < ksteps; ++kk) {
    const int koff = kk * 32 + ((kk >> 1) ? kpad : 0) + (lane >> 4) * 8;
    half8v a[2], b[2];
#pragma unroll
    for (int m = 0; m < 2; ++m)
      a[m] = *(const half8v*)(XB + (wr * 32 + m * 16 + (lane & 15)) * xstr + koff);
#pragma unroll
    for (int n = 0; n < 2; ++n)
      b[n] = *(const half8v*)(YB + (wc * 32 + n * 16 + (lane & 15)) * ystr + koff);
#pragma unroll
    for (int m = 0; m < 2; ++m)
#pragma unroll
      for (int n = 0; n < 2; ++n)
        acc[m][n] = __builtin_amdgcn_mfma_f32_16x16x32_f16(a[m], b[n], acc[m][n], 0, 0, 0);
  }
}

__global__ __launch_bounds__(256) void scan_chunked(
    const float* __restrict__ qc, const float* __restrict__ kc, const float* __restrict__ vc,
    const float* __restrict__ abi, float* __restrict__ o)
{
  __shared__ float    STf[64 * 66];       // state S^T [v][d], persistent
  __shared__ _Float16 Y2[64 * 144];       // [v][0:64]=S0^T f16, [72:136]=U^T
  __shared__ _Float16 X2[64 * 144];       // [t][0:64]=e^g q,   [72:136]=P
  __shared__ _Float16 Kf[64 * 72];        // k rows
  __shared__ _Float16 Qf[64 * 72];        // q rows (raw)
  __shared__ _Float16 KsT[64 * 72];       // [d][t] = e^{gC-g_t} k_t[d]
  __shared__ _Float16 Tf[64 * 72];        // (I+A)^-1 f16
  __shared__ float    Af[64 * 66];        // A, then T f32 (in place)
  __shared__ _Float16 RT[64 * 72];        // RHS^T [v][t]
  __shared__ float    tmpf[1088];         // combine scratch (padded)
  __shared__ float    g_s[64], eg_s[64], bet_s[64], betg_s[64], eKs_s[64];
  __shared__ float    egC_s;

  const int blk  = blockIdx.x;
  const int bh   = blk % NBH;
  const int vb   = blk / NBH;            // 0..1
  const int b    = bh / HH, h = bh % HH;
  const int tid  = threadIdx.x;
  const int lane = tid & 63;
  const int w    = tid >> 6;
  const int wr   = w >> 1, wc = w & 1;

  // zero state
  for (int i = tid; i < 64 * 66; i += 256) STf[i] = 0.f;
  __syncthreads();

  for (int c = 0; c < TT / 64; ++c) {
    const int c0 = c * 64;

    // ---- ph0: per-chunk scalars (wave 0) ----
    if (tid < 64) {
      float2 ab = *(const float2*)(abi + ((size_t)bh * TT + c0 + tid) * 2);
      float gg = logf(ab.x);
#pragma unroll
      for (int off = 1; off < 64; off <<= 1) {
        float up = __shfl_up(gg, off, 64);
        if (tid >= off) gg += up;
      }
      float gC = __shfl(gg, 63, 64);
      g_s[tid]    = gg;
      eg_s[tid]   = expf(gg);
      bet_s[tid]  = ab.y;
      betg_s[tid] = ab.y * expf(gg);
      eKs_s[tid]  = expf(gC - gg);
      if (tid == 0) egC_s = expf(gC);
    }
    __syncthreads();

    // ---- ph1: load K,Q; build Kf,KsT,Qf,Qg(X2 left); cast ST->Y2 left ----
    {
      const int t  = tid >> 2;
      const int dg = tid & 3;
      const float* krow = kc + ((size_t)bh * TT + c0 + t) * 64 + dg * 16;
      const float* qrow = qc + ((size_t)bh * TT + c0 + t) * 64 + dg * 16;
      const float ekt = eKs_s[t], egt = eg_s[t];
#pragma unroll
      for (int q4 = 0; q4 < 4; ++q4) {
        float4 kv = *(const float4*)(krow + q4 * 4);
        float4 qv = *(const float4*)(qrow + q4 * 4);
        const int d = dg * 16 + q4 * 4;
        const float kf[4] = {kv.x, kv.y, kv.z, kv.w};
        const float qf[4] = {qv.x, qv.y, qv.z, qv.w};
#pragma unroll
        for (int e = 0; e < 4; ++e) {
          Kf[t * 72 + d + e]  = (_Float16)kf[e];
          KsT[(d + e) * 72 + t] = (_Float16)(kf[e] * ekt);
          Qf[t * 72 + d + e]  = (_Float16)qf[e];
          X2[t * 144 + d + e] = (_Float16)(qf[e] * egt);
        }
      }
      // ST -> Y2 left (f16)
      const int v = tid >> 2;
#pragma unroll
      for (int q4 = 0; q4 < 4; ++q4) {
        const int d = dg * 16 + q4 * 4;
#pragma unroll
        for (int e = 0; e < 4; ++e)
          Y2[v * 144 + d + e] = (_Float16)STf[v * 66 + d + e];
      }
    }
    __syncthreads();

    // ---- ph2: P1 = K K^T -> A ----
    {
      f32x4 acc[2][2];
      gemm64(Kf, 72, Kf, 72, wr, wc, lane, 2, 0, acc);
#pragma unroll
      for (int m = 0; m < 2; ++m)
#pragma unroll
        for (int n = 0; n < 2; ++n)
#pragma unroll
          for (int j = 0; j < 4; ++j) {
            const int row = wr * 32 + m * 16 + (lane >> 4) * 4 + j;
            const int col = wc * 32 + n * 16 + (lane & 15);
            float v = 0.f;
            if (col < row)
              v = bet_s[row] * expf(g_s[row] - g_s[col]) * acc[m][n][j];
            Af[row * 66 + col] = v;
          }
    }
    __syncthreads();

    // ---- ph3: T = (I+A)^-1 in place (blocked) ----
    // 3a: 4 diagonal 16x16 inverses, one per wave (lanes 0..15 active)
    if (lane < 16) {
      const int R = w * 16;
      Af[R * 66 + R + lane] = (lane == 0) ? 1.f : 0.f;
      for (int t = 1; t < 16; ++t) {
        float s = 0.f;
        for (int i = 0; i < t; ++i)
          s = fmaf(Af[(R + t) * 66 + R + i], Af[(R + i) * 66 + R + lane], s);
        Af[(R + t) * 66 + R + lane] = ((lane == t) ? 1.f : 0.f) - s;
      }
    }
    __syncthreads();
    // 3b: level-1 combine: E_p = -T2p A21p T1p  (p=0,1)
    {
      const int r = (tid >> 4) & 15, cidx = tid & 15;
#pragma unroll
      for (int p = 0; p < 2; ++p) {
        float s = 0.f;
        for (int i = 0; i < 16; ++i)
          s = fmaf(Af[(p * 32 + 16 + r) * 66 + p * 32 + i],
                   Af[(p * 32 + i) * 66 + p * 32 + cidx], s);
        tmpf[p * 272 + r * 17 + cidx] = s;
      }
      __syncthreads();
#pragma unroll
      for (int p = 0; p < 2; ++p) {
        float s = 0.f;
        for (int i = 0; i < 16; ++i)
          s = fmaf(Af[(p * 32 + 16 + r) * 66 + p * 32 + 16 + i],
                   tmpf[p * 272 + i * 17 + cidx], s);
        __syncthreads();
        Af[(p * 32 + 16 + r) * 66 + p * 32 + cidx] = -s;
        __syncthreads();
      }
    }
    // 3c: level-2 combine: F = -Tl (A[32:64][0:32] Tu)
    {
#pragma unroll
      for (int rep = 0; rep < 4; ++rep) {
        const int idx = tid + rep * 256;
        const int r = idx >> 5, cidx = idx & 31;
        float s = 0.f;
        for (int i = 0; i < 32; ++i)
          s = fmaf(Af[(32 + r) * 66 + i], Af[i * 66 + cidx], s);
        tmpf[r * 33 + cidx] = s;
      }
      __syncthreads();
#pragma unroll
      for (int rep = 0; rep < 4; ++rep) {
        const int idx = tid + rep * 256;
        const int r = idx >> 5, cidx = idx & 31;
        float s = 0.f;
        for (int i = 0; i < 32; ++i)
          s = fmaf(Af[(32 + r) * 66 + 32 + i], tmpf[i * 33 + cidx], s);
        __syncthreads();
        Af[(32 + r) * 66 + cidx] = -s;
        __syncthreads();
      }
    }
    // ph4: cast T -> f16
    {
      const int t = tid >> 2, qg = tid & 3;
#pragma unroll
      for (int e = 0; e < 16; ++e) {
        const int i = qg * 16 + e;
        Tf[t * 72 + i] = (_Float16)Af[t * 66 + i];
      }
    }
    __syncthreads();

    // ---- ph5: P3 = K @ S0 -> RHS^T ----
    {
      f32x4 acc[2][2];
      gemm64(Kf, 72, Y2, 144, wr, wc, lane, 2, 0, acc);
#pragma unroll
      for (int m = 0; m < 2; ++m)
#pragma unroll
        for (int n = 0; n < 2; ++n)
#pragma unroll
          for (int j = 0; j < 4; ++j) {
            const int row = wr * 32 + m * 16 + (lane >> 4) * 4 + j;   // t
            const int col = wc * 32 + n * 16 + (lane & 15);           // v
            const float vload = vc[((size_t)bh * TT + c0 + row) * 128 + vb * 64 + col];
            RT[col * 72 + row] = (_Float16)(vload - betg_s[row] * acc[m][n][j]);
          }
    }
    __syncthreads();

    // ---- ph6: P4 = T @ RHS -> U^T (Y2 right) ----
    {
      f32x4 acc[2][2];
      gemm64(Tf, 72, RT, 72, wr, wc, lane, 2, 0, acc);
#pragma unroll
      for (int m = 0; m < 2; ++m)
#pragma unroll
        for (int n = 0; n < 2; ++n)
#pragma unroll
          for (int j = 0; j < 4; ++j) {
            const int row = wr * 32 + m * 16 + (lane >> 4) * 4 + j;   // t
            const int col = wc * 32 + n * 16 + (lane & 15);           // v
            Y2[col * 144 + 72 + row] = (_Float16)acc[m][n][j];
          }
    }
    __syncthreads();

    // ---- ph7: P6 = Ks^T @ U -> S update ----
    {
      f32x4 acc[2][2];
      gemm64(KsT, 72, Y2 + 72, 144, wr, wc, lane, 2, 0, acc);
      const float egC = egC_s;
#pragma unroll
      for (int m = 0; m < 2; ++m)
#pragma unroll
        for (int n = 0; n < 2; ++n)
#pragma unroll
          for (int j = 0; j < 4; ++j) {
            const int row = wr * 32 + m * 16 + (lane >> 4) * 4 + j;   // d
            const int col = wc * 32 + n * 16 + (lane & 15);           // v
            STf[col * 66 + row] = egC * STf[col * 66 + row] + acc[m][n][j];
          }
    }
    __syncthreads();

    // ---- ph8: P2 = Q @ K^T -> P (X2 right) ----
    {
      f32x4 acc[2][2];
      gemm64(Qf, 72, Kf, 72, wr, wc, lane, 2, 0, acc);
#pragma unroll
      for (int m = 0; m < 2; ++m)
#pragma unroll
        for (int n = 0; n < 2; ++n)
#pragma unroll
          for (int j = 0; j < 4; ++j) {
            const int row = wr * 32 + m * 16 + (lane >> 4) * 4 + j;   // t
            const int col = wc * 32 + n * 16 + (lane & 15);           // i
            float v = 0.f;
            if (col <= row) v = expf(g_s[row] - g_s[col]) * acc[m][n][j];
            X2[row * 144 + 72 + col] = (_Float16)v;
          }
    }
    __syncthreads();

    // ---- ph9: P5 = [Qg|P] @ [S0^T|U^T]^T -> o ----
    {
      f32x4 acc[2][2];
      gemm64(X2, 144, Y2, 144, wr, wc, lane, 4, 8, acc);
#pragma unroll
      for (int m = 0; m < 2; ++m)
#pragma unroll
        for (int n = 0; n < 2; ++n)
#pragma unroll
          for (int j = 0; j < 4; ++j) {
            const int row = wr * 32 + m * 16 + (lane >> 4) * 4 + j;   // t
            const int col = wc * 32 + n * 16 + (lane & 15);           // v
            o[(((size_t)b * TT + c0 + row) * HH + h) * 128 + vb * 64 + col] = acc[m][n][j];
          }
    }
    __syncthreads();
  }
}

// ---------------------------------------------------------------------------
// RMS norm over 128 + SiLU gate; emits fp16 for the final GEMM.
// ---------------------------------------------------------------------------
__global__ void rmsgate_kernel(const float* __restrict__ o, const float* __restrict__ gpre,
                               ushort* __restrict__ gof)
{
  int gid  = blockIdx.x * blockDim.x + threadIdx.x;
  int wid  = gid >> 6;
  int lane = threadIdx.x & 63;
  if (wid >= BB * TT * HH) return;
  int h = wid % HH;
  int m = wid / HH;
  const float* orow = o + (size_t)wid * 128;
  float2 ov = *(const float2*)(orow + lane * 2);
  float ss = ov.x * ov.x + ov.y * ov.y;
#pragma unroll
  for (int mm = 32; mm >= 1; mm >>= 1) ss += __shfl_xor(ss, mm, 64);
  float scale = rsqrtf(ss * (1.f / 128.f) + EPSF);
  const float* gr = gpre + (size_t)m * TVv + h * 128 + lane * 2;
  float o0 = ov.x * scale * siluf(gr[0]);
  float o1 = ov.y * scale * siluf(gr[1]);
  *(uint*)(gof + (size_t)m * TVv + h * 128 + lane * 2) = pk2h(o0, o1);
}

// ---------------------------------------------------------------------------
extern "C" void kernel_launch(void* const* d_in, const int* in_sizes, int n_in,
                              void* d_out, int out_size, void* d_ws, size_t ws_size,
                              hipStream_t stream) {
  (void)in_sizes; (void)n_in; (void)out_size; (void)ws_size;
  const float* x       = (const float*)d_in[0];
  const float* w_q     = (const float*)d_in[1];
  const float* w_k     = (const float*)d_in[2];
  const float* w_v     = (const float*)d_in[3];
  const float* w_a     = (const float*)d_in[4];
  const float* w_b     = (const float*)d_in[5];
  const float* w_g     = (const float*)d_in[6];
  const float* w_out   = (const float*)d_in[7];
  const float* A_log   = (const float*)d_in[8];
  const float* dt_bias = (const float*)d_in[9];
  const float* qcw     = (const float*)d_in[10];
  const float* kcw     = (const float*)d_in[11];
  const float* vcw     = (const float*)d_in[12];

  float* ws      = (float*)d_ws;
  float* qkv_pre = ws;
  float* g_pre   = ws + 6291456;
  float* Cu      = ws + 9437184;
  float* abi     = ws + 15728640;

  ushort* xf    = (ushort*)Cu;
  ushort* wcat  = (ushort*)(Cu + 1572864);

  float* qc = Cu;
  float* kc = Cu + 1572864;
  float* vc = Cu + 3145728;

  ushort* woutf = (ushort*)Cu;

  float*  o   = qkv_pre;
  ushort* gof = (ushort*)(qkv_pre + 3145728);

  const int M = BB * TT;  // 2048
  dim3 blk(256);

  // 1) fp16 casts
  cast_f16_kernel<<<1536, blk, 0, stream>>>(x, xf);
  cast_w4_kernel<<<3456, blk, 0, stream>>>(w_q, w_k, w_v, w_g, wcat);

  // 2) fused qkv+g projection
  gemm_f16<<<dim3(NQKVG / 128, M / 128), blk, 0, stream>>>(
      xf, wcat, qkv_pre, g_pre, M, NQKVG, DD, CQKV, TVv, CQKV);

  // 3) gating coefficients
  gate_kernel<<<M, blk, 0, stream>>>(x, w_a, w_b, A_log, dt_bias, abi);

  // 4) conv + SiLU + L2 norm
  conv_silu_kernel<<<24576, blk, 0, stream>>>(qkv_pre, qcw, kcw, vcw, qc, kc, vc);

  // 5) chunked WY delta-rule scan (16 serial chunks, MFMA)
  scan_chunked<<<48, blk, 0, stream>>>(qc, kc, vc, abi, o);

  // 6) cast w_out
  cast_f16_kernel<<<1152, blk, 0, stream>>>(w_out, woutf);

  // 7) RMS norm + SiLU gate
  rmsgate_kernel<<<6144, blk, 0, stream>>>(o, g_pre, gof);

  // 8) output projection
  gemm_f16<<<dim3(TVv / 128, M / 128), blk, 0, stream>>>(
      gof, woutf, (float*)d_out, (float*)d_out, M, TVv, DD, TVv, TVv, TVv);
}

// Round 16
// 326.999 us; speedup vs baseline: 1.0706x; 1.0706x over previous
//
#include <hip/hip_runtime.h>
#include <math.h>

#define BB 2
#define TT 1024
#define DD 1536
#define HH 12
#define TQK 768
#define TVv 1536
#define CQKV 3072
#define NQKVG 4608
#define EPSF 1e-6f
#define NBH (BB * HH)   // 24

typedef __attribute__((ext_vector_type(8))) _Float16 half8v;
typedef __attribute__((ext_vector_type(4))) float f32x4;

__device__ __forceinline__ float siluf(float x) { return x / (1.f + expf(-x)); }

__device__ __forceinline__ uint pk2h(float a, float b) {
  union { _Float16 h[2]; uint u; } p;
  p.h[0] = (_Float16)a; p.h[1] = (_Float16)b;
  return p.u;
}

// async global->LDS (GEMM staging)
__device__ __forceinline__ void gload16(const void* g, void* l) {
  __builtin_amdgcn_global_load_lds(
      (const __attribute__((address_space(1))) void*)g,
      (__attribute__((address_space(3))) void*)l, 16, 0, 0);
}

// ---------------------------------------------------------------------------
// fp16 MFMA GEMM (proven): C = X @ W^T -> f32.
// ---------------------------------------------------------------------------
__global__ __launch_bounds__(256) void gemm_f16(
    const ushort* __restrict__ X, const ushort* __restrict__ W,
    float* __restrict__ C1, float* __restrict__ C2,
    int M, int N, int K, int ldc1, int ldc2, int nsplit)
{
  __shared__ ushort Ah[128 * 64];
  __shared__ ushort Bh[128 * 64];
  const int tid  = threadIdx.x;
  const int lane = tid & 63;
  const int w    = tid >> 6;
  const int wr   = w >> 1, wc = w & 1;
  const int r0   = blockIdx.y * 128, c0 = blockIdx.x * 128;

  const int dr   = lane >> 3;
  const int slot = (lane & 7) ^ dr;

  f32x4 acc[4][4];
#pragma unroll
  for (int m = 0; m < 4; ++m)
#pragma unroll
    for (int n = 0; n < 4; ++n)
#pragma unroll
      for (int j = 0; j < 4; ++j) acc[m][n][j] = 0.f;

  for (int k0 = 0; k0 < K; k0 += 64) {
#pragma unroll
    for (int j = 0; j < 4; ++j) {
      const int row  = (w * 4 + j) * 8 + dr;
      const size_t xo = (size_t)(r0 + row) * K + k0 + slot * 8;
      const size_t wo = (size_t)(c0 + row) * K + k0 + slot * 8;
      const int ldso = (w * 4 + j) * 512;
      gload16(X + xo, Ah + ldso);
      gload16(W + wo, Bh + ldso);
    }
    __syncthreads();
#pragma unroll
    for (int kk = 0; kk < 2; ++kk) {
      const int kc8 = kk * 4 + (lane >> 4);
      const int sw  = (kc8 ^ (lane & 7)) << 3;
      half8v a[4], b[4];
#pragma unroll
      for (int m = 0; m < 4; ++m)
        a[m] = *(const half8v*)(Ah + (wr * 64 + m * 16 + (lane & 15)) * 64 + sw);
#pragma unroll
      for (int n = 0; n < 4; ++n)
        b[n] = *(const half8v*)(Bh + (wc * 64 + n * 16 + (lane & 15)) * 64 + sw);
#pragma unroll
      for (int m = 0; m < 4; ++m)
#pragma unroll
        for (int n = 0; n < 4; ++n)
          acc[m][n] = __builtin_amdgcn_mfma_f32_16x16x32_f16(a[m], b[n], acc[m][n], 0, 0, 0);
    }
    __syncthreads();
  }

  float* Cp; int ldc, cc0;
  if (c0 < nsplit) { Cp = C1; ldc = ldc1; cc0 = c0; }
  else             { Cp = C2; ldc = ldc2; cc0 = c0 - nsplit; }

  const int crow = (lane >> 4) * 4;
  const int ccol = lane & 15;
#pragma unroll
  for (int m = 0; m < 4; ++m)
#pragma unroll
    for (int j = 0; j < 4; ++j) {
      float* cp = Cp + (size_t)(r0 + wr * 64 + m * 16 + crow + j) * ldc + cc0 + wc * 64 + ccol;
#pragma unroll
      for (int n = 0; n < 4; ++n) cp[n * 16] = acc[m][n][j];
    }
}

// ---------------------------------------------------------------------------
// f32 -> fp16 casts.
// ---------------------------------------------------------------------------
__device__ __forceinline__ void cast8_store(const float* f, ushort* dst, size_t e)
{
  uint4 pk;
  pk.x = pk2h(f[0], f[1]); pk.y = pk2h(f[2], f[3]);
  pk.z = pk2h(f[4], f[5]); pk.w = pk2h(f[6], f[7]);
  *(uint4*)(dst + e) = pk;
}

__global__ void cast_f16_kernel(const float* __restrict__ src, ushort* __restrict__ dst)
{
  int cid = blockIdx.x * blockDim.x + threadIdx.x;
  size_t e = (size_t)cid * 8;
  float f[8];
  *(float4*)(f)     = *(const float4*)(src + e);
  *(float4*)(f + 4) = *(const float4*)(src + e + 4);
  cast8_store(f, dst, e);
}

__global__ void cast_w4_kernel(const float* __restrict__ wq, const float* __restrict__ wk,
                               const float* __restrict__ wv, const float* __restrict__ wg,
                               ushort* __restrict__ dst)
{
  int cid = blockIdx.x * blockDim.x + threadIdx.x;
  size_t e = (size_t)cid * 8;
  const float* src; size_t off;
  if (e < 1179648)      { src = wq; off = e; }
  else if (e < 2359296) { src = wk; off = e - 1179648; }
  else if (e < 4718592) { src = wv; off = e - 2359296; }
  else                  { src = wg; off = e - 4718592; }
  float f[8];
  *(float4*)(f)     = *(const float4*)(src + off);
  *(float4*)(f + 4) = *(const float4*)(src + off + 4);
  cast8_store(f, dst, e);
}

// ---------------------------------------------------------------------------
// Causal depthwise conv (K=4) + SiLU + fused L2-norm (q,k heads).
// ---------------------------------------------------------------------------
__global__ void conv_silu_kernel(
    const float* __restrict__ pre,
    const float* __restrict__ qw, const float* __restrict__ kw, const float* __restrict__ vw,
    float* __restrict__ qc, float* __restrict__ kc, float* __restrict__ vc)
{
  int idx = blockIdx.x * blockDim.x + threadIdx.x;
  int c  = idx % CQKV;
  int bt = idx / CQKV;
  int t  = bt % TT;
  int b  = bt / TT;

  const float* wp;
  if (c < TQK)          wp = qw + (size_t)c * 4;
  else if (c < 2 * TQK) wp = kw + (size_t)(c - TQK) * 4;
  else                  wp = vw + (size_t)(c - 2 * TQK) * 4;

  float s = 0.f;
#pragma unroll
  for (int j = 0; j < 4; ++j) {
    int ts = t - 3 + j;
    if (ts >= 0) s = fmaf(pre[(size_t)(b * TT + ts) * CQKV + c], wp[j], s);
  }
  s = siluf(s);

  if (c < 2 * TQK) {
    float ss = s * s;
#pragma unroll
    for (int m = 32; m >= 1; m >>= 1) ss += __shfl_xor(ss, m, 64);
    s = s / fmaxf(sqrtf(ss), EPSF);
  }

  if (c < TQK) {
    int h = c >> 6, d = c & 63;
    qc[((size_t)(b * HH + h) * TT + t) * 64 + d] = s;
  } else if (c < 2 * TQK) {
    int c2 = c - TQK; int h = c2 >> 6, d = c2 & 63;
    kc[((size_t)(b * HH + h) * TT + t) * 64 + d] = s;
  } else {
    int c2 = c - 2 * TQK; int h = c2 >> 7, d = c2 & 127;
    vc[((size_t)(b * HH + h) * TT + t) * 128 + d] = s;
  }
}

// ---------------------------------------------------------------------------
// Gating: block per row; writes interleaved (alpha,beta).
// ---------------------------------------------------------------------------
__global__ __launch_bounds__(256) void gate_kernel(
    const float* __restrict__ x, const float* __restrict__ w_a, const float* __restrict__ w_b,
    const float* __restrict__ A_log, const float* __restrict__ dt_bias,
    float* __restrict__ abi)
{
  const int m    = blockIdx.x;
  const int w    = threadIdx.x >> 6;
  const int lane = threadIdx.x & 63;
  const float* xr = x + (size_t)m * DD;
  float xv[24];
#pragma unroll
  for (int i = 0; i < 24; ++i) xv[i] = xr[lane + i * 64];
  const int b = m / TT, t = m % TT;
#pragma unroll
  for (int j = 0; j < 6; ++j) {
    int o = w * 6 + j;
    bool isA = o < HH;
    int h = isA ? o : o - HH;
    const float* wr = (isA ? w_a : w_b) + (size_t)h * DD;
    float s = 0.f;
#pragma unroll
    for (int i = 0; i < 24; ++i) s = fmaf(xv[i], wr[lane + i * 64], s);
#pragma unroll
    for (int mm = 32; mm >= 1; mm >>= 1) s += __shfl_xor(s, mm, 64);
    if (lane == 0) {
      size_t idx = ((size_t)(b * HH + h) * TT + t) * 2;
      if (isA) {
        float a  = s + dt_bias[h];
        float sp = (a > 20.f) ? a : log1pf(expf(a));
        abi[idx] = expf(-expf(A_log[h]) * sp);
      } else {
        abi[idx + 1] = 2.f / (1.f + expf(-s));
      }
    }
  }
}

// ---------------------------------------------------------------------------
// CHUNKED gated delta rule (WY form), C=64, 16 serial chunks. R15-verified
// algebra; R16 = barrier-count cut 22->11/chunk (out-of-place T build in Tg,
// merged phases) + stride padding 66->67 (bank conflicts).
// ---------------------------------------------------------------------------
__device__ __forceinline__ void gemm64(
    const _Float16* XB, int xstr, const _Float16* YB, int ystr,
    int wr, int wc, int lane, int ksteps, int kpad, f32x4 acc[2][2])
{
#pragma unroll
  for (int m = 0; m < 2; ++m)
#pragma unroll
    for (int n = 0; n < 2; ++n)
#pragma unroll
      for (int j = 0; j < 4; ++j) acc[m][n][j] = 0.f;
#pragma unroll 4
  for (int kk = 0; kk < ksteps; ++kk) {
    const int koff = kk * 32 + ((kk >> 1) ? kpad : 0) + (lane >> 4) * 8;
    half8v a[2], b[2];
#pragma unroll
    for (int m = 0; m < 2; ++m)
      a[m] = *(const half8v*)(XB + (wr * 32 + m * 16 + (lane & 15)) * xstr + koff);
#pragma unroll
    for (int n = 0; n < 2; ++n)
      b[n] = *(const half8v*)(YB + (wc * 32 + n * 16 + (lane & 15)) * ystr + koff);
#pragma unroll
    for (int m = 0; m < 2; ++m)
#pragma unroll
      for (int n = 0; n < 2; ++n)
        acc[m][n] = __builtin_amdgcn_mfma_f32_16x16x32_f16(a[m], b[n], acc[m][n], 0, 0, 0);
  }
}

__global__ __launch_bounds__(256) void scan_chunked(
    const float* __restrict__ qc, const float* __restrict__ kc, const float* __restrict__ vc,
    const float* __restrict__ abi, float* __restrict__ o)
{
  __shared__ float    STf[64 * 67];       // state S^T [v][d], persistent
  __shared__ float    Af[64 * 67];        // A (kept intact)
  __shared__ float    Tg[64 * 67];        // T built out-of-place (f32)
  __shared__ _Float16 Y2[64 * 144];       // [v][0:64]=S0^T f16, [72:136]=U^T
  __shared__ _Float16 X2[64 * 144];       // [t][0:64]=e^g q,   [72:136]=P
  __shared__ _Float16 Kf[64 * 72];        // k rows
  __shared__ _Float16 Qf[64 * 72];        // q rows
  __shared__ _Float16 KsT[64 * 72];       // [d][t] = e^{gC-g_t} k_t[d]
  __shared__ _Float16 Tf[64 * 72];        // T f16
  __shared__ _Float16 RT[64 * 72];        // RHS^T [v][t]
  __shared__ float    tmpf[1088];
  __shared__ float    g_s[64], eg_s[64], bet_s[64], betg_s[64], eKs_s[64];
  __shared__ float    egC_s;

  const int blk  = blockIdx.x;
  const int bh   = blk % NBH;
  const int vb   = blk / NBH;            // 0..1
  const int b    = bh / HH, h = bh % HH;
  const int tid  = threadIdx.x;
  const int lane = tid & 63;
  const int w    = tid >> 6;
  const int wr   = w >> 1, wc = w & 1;

  for (int i = tid; i < 64 * 67; i += 256) STf[i] = 0.f;
  __syncthreads();

  for (int c = 0; c < TT / 64; ++c) {
    const int c0 = c * 64;

    // ---- ph0: per-chunk scalars (wave 0) ---- [bar 1]
    if (tid < 64) {
      float2 ab = *(const float2*)(abi + ((size_t)bh * TT + c0 + tid) * 2);
      float gg = logf(ab.x);
#pragma unroll
      for (int off = 1; off < 64; off <<= 1) {
        float up = __shfl_up(gg, off, 64);
        if (tid >= off) gg += up;
      }
      float gC = __shfl(gg, 63, 64);
      g_s[tid]    = gg;
      eg_s[tid]   = expf(gg);
      bet_s[tid]  = ab.y;
      betg_s[tid] = ab.y * expf(gg);
      eKs_s[tid]  = expf(gC - gg);
      if (tid == 0) egC_s = expf(gC);
    }
    __syncthreads();

    // ---- ph1: load K,Q; build Kf,KsT,Qf,X2-left; ST->Y2-left; zero Tg ---- [bar 2]
    {
      const int t  = tid >> 2;
      const int dg = tid & 3;
      const float* krow = kc + ((size_t)bh * TT + c0 + t) * 64 + dg * 16;
      const float* qrow = qc + ((size_t)bh * TT + c0 + t) * 64 + dg * 16;
      const float ekt = eKs_s[t], egt = eg_s[t];
#pragma unroll
      for (int q4 = 0; q4 < 4; ++q4) {
        float4 kv = *(const float4*)(krow + q4 * 4);
        float4 qv = *(const float4*)(qrow + q4 * 4);
        const int d = dg * 16 + q4 * 4;
        const float kf[4] = {kv.x, kv.y, kv.z, kv.w};
        const float qf[4] = {qv.x, qv.y, qv.z, qv.w};
#pragma unroll
        for (int e = 0; e < 4; ++e) {
          Kf[t * 72 + d + e]    = (_Float16)kf[e];
          KsT[(d + e) * 72 + t] = (_Float16)(kf[e] * ekt);
          Qf[t * 72 + d + e]    = (_Float16)qf[e];
          X2[t * 144 + d + e]   = (_Float16)(qf[e] * egt);
        }
      }
      const int v = tid >> 2;
#pragma unroll
      for (int q4 = 0; q4 < 4; ++q4) {
        const int d = dg * 16 + q4 * 4;
#pragma unroll
        for (int e = 0; e < 4; ++e)
          Y2[v * 144 + d + e] = (_Float16)STf[v * 67 + d + e];
      }
      for (int i = tid; i < 64 * 67; i += 256) Tg[i] = 0.f;
    }
    __syncthreads();

    // ---- ph2: A = mask(K K^T), P = mask(Q K^T) (one barrier) ---- [bar 3]
    {
      f32x4 accA[2][2], accP[2][2];
      gemm64(Kf, 72, Kf, 72, wr, wc, lane, 2, 0, accA);
      gemm64(Qf, 72, Kf, 72, wr, wc, lane, 2, 0, accP);
#pragma unroll
      for (int m = 0; m < 2; ++m)
#pragma unroll
        for (int n = 0; n < 2; ++n)
#pragma unroll
          for (int j = 0; j < 4; ++j) {
            const int row = wr * 32 + m * 16 + (lane >> 4) * 4 + j;
            const int col = wc * 32 + n * 16 + (lane & 15);
            const float eg = expf(g_s[row] - g_s[col]);
            Af[row * 67 + col] = (col < row) ? bet_s[row] * eg * accA[m][n][j] : 0.f;
            X2[row * 144 + 72 + col] =
                (col <= row) ? (_Float16)(eg * accP[m][n][j]) : (_Float16)0.f;
          }
    }
    __syncthreads();

    // ---- ph3a: 4 diagonal 16x16 inverses into Tg (intra-wave only) ---- [bar 4]
    if (lane < 16) {
      const int R = w * 16;
      Tg[R * 67 + R + lane] = (lane == 0) ? 1.f : 0.f;
      for (int t = 1; t < 16; ++t) {
        float s = 0.f;
        for (int i = 0; i < t; ++i)
          s = fmaf(Af[(R + t) * 67 + R + i], Tg[(R + i) * 67 + R + lane], s);
        Tg[(R + t) * 67 + R + lane] = ((lane == t) ? 1.f : 0.f) - s;
      }
    }
    __syncthreads();

    // ---- ph3b-1: tmp_p = A21p @ T1p ---- [bar 5]
    {
      const int r = (tid >> 4) & 15, cx = tid & 15;
#pragma unroll
      for (int p = 0; p < 2; ++p) {
        float s = 0.f;
        for (int i = 0; i < 16; ++i)
          s = fmaf(Af[(p * 32 + 16 + r) * 67 + p * 32 + i],
                   Tg[(p * 32 + i) * 67 + p * 32 + cx], s);
        tmpf[p * 272 + r * 17 + cx] = s;
      }
    }
    __syncthreads();
    // ---- ph3b-2: E_p = -T2p @ tmp_p ---- [bar 6]
    {
      const int r = (tid >> 4) & 15, cx = tid & 15;
#pragma unroll
      for (int p = 0; p < 2; ++p) {
        float s = 0.f;
        for (int i = 0; i < 16; ++i)
          s = fmaf(Tg[(p * 32 + 16 + r) * 67 + p * 32 + 16 + i],
                   tmpf[p * 272 + i * 17 + cx], s);
        Tg[(p * 32 + 16 + r) * 67 + p * 32 + cx] = -s;
      }
    }
    __syncthreads();
    // ---- ph3c-1: tmp2 = A[32:64][0:32] @ Tu ---- [bar 7]
    {
#pragma unroll
      for (int rep = 0; rep < 4; ++rep) {
        const int idx = tid + rep * 256;
        const int r = idx >> 5, cx = idx & 31;
        float s = 0.f;
        for (int i = 0; i < 32; ++i)
          s = fmaf(Af[(32 + r) * 67 + i], Tg[i * 67 + cx], s);
        tmpf[r * 33 + cx] = s;
      }
    }
    __syncthreads();
    // ---- ph3c-2: F = -Tl @ tmp2 ---- [bar 8]
    {
#pragma unroll
      for (int rep = 0; rep < 4; ++rep) {
        const int idx = tid + rep * 256;
        const int r = idx >> 5, cx = idx & 31;
        float s = 0.f;
        for (int i = 0; i < 32; ++i)
          s = fmaf(Tg[(32 + r) * 67 + 32 + i], tmpf[i * 33 + cx], s);
        Tg[(32 + r) * 67 + cx] = -s;
      }
    }
    __syncthreads();

    // ---- ph45: cast Tg->Tf f16  +  RHS^T = V - diag(betg) K@S0 ---- [bar 9]
    {
      const int t = tid >> 2, qg = tid & 3;
#pragma unroll
      for (int e = 0; e < 16; ++e) {
        const int i = qg * 16 + e;
        Tf[t * 72 + i] = (_Float16)Tg[t * 67 + i];
      }
      f32x4 acc[2][2];
      gemm64(Kf, 72, Y2, 144, wr, wc, lane, 2, 0, acc);
#pragma unroll
      for (int m = 0; m < 2; ++m)
#pragma unroll
        for (int n = 0; n < 2; ++n)
#pragma unroll
          for (int j = 0; j < 4; ++j) {
            const int row = wr * 32 + m * 16 + (lane >> 4) * 4 + j;   // t
            const int col = wc * 32 + n * 16 + (lane & 15);           // v
            const float vload = vc[((size_t)bh * TT + c0 + row) * 128 + vb * 64 + col];
            RT[col * 72 + row] = (_Float16)(vload - betg_s[row] * acc[m][n][j]);
          }
    }
    __syncthreads();

    // ---- ph6: U^T = (T @ RHS)^T -> Y2 right ---- [bar 10]
    {
      f32x4 acc[2][2];
      gemm64(Tf, 72, RT, 72, wr, wc, lane, 2, 0, acc);
#pragma unroll
      for (int m = 0; m < 2; ++m)
#pragma unroll
        for (int n = 0; n < 2; ++n)
#pragma unroll
          for (int j = 0; j < 4; ++j) {
            const int row = wr * 32 + m * 16 + (lane >> 4) * 4 + j;   // t
            const int col = wc * 32 + n * 16 + (lane & 15);           // v
            Y2[col * 144 + 72 + row] = (_Float16)acc[m][n][j];
          }
    }
    __syncthreads();

    // ---- ph79: S = egC*S + Ks^T@U  AND  O = [Qg|P]@[S0^T|U^T]^T ---- [bar 11]
    {
      f32x4 accS[2][2], accO[2][2];
      gemm64(KsT, 72, Y2 + 72, 144, wr, wc, lane, 2, 0, accS);
      gemm64(X2, 144, Y2, 144, wr, wc, lane, 4, 8, accO);
      const float egC = egC_s;
#pragma unroll
      for (int m = 0; m < 2; ++m)
#pragma unroll
        for (int n = 0; n < 2; ++n)
#pragma unroll
          for (int j = 0; j < 4; ++j) {
            const int row = wr * 32 + m * 16 + (lane >> 4) * 4 + j;   // d (S) / t (O)
            const int col = wc * 32 + n * 16 + (lane & 15);           // v
            STf[col * 67 + row] = egC * STf[col * 67 + row] + accS[m][n][j];
            o[(((size_t)b * TT + c0 + row) * HH + h) * 128 + vb * 64 + col] = accO[m][n][j];
          }
    }
    __syncthreads();
  }
}

// ---------------------------------------------------------------------------
// RMS norm over 128 + SiLU gate; emits fp16 for the final GEMM.
// ---------------------------------------------------------------------------
__global__ void rmsgate_kernel(const float* __restrict__ o, const float* __restrict__ gpre,
                               ushort* __restrict__ gof)
{
  int gid  = blockIdx.x * blockDim.x + threadIdx.x;
  int wid  = gid >> 6;
  int lane = threadIdx.x & 63;
  if (wid >= BB * TT * HH) return;
  int h = wid % HH;
  int m = wid / HH;
  const float* orow = o + (size_t)wid * 128;
  float2 ov = *(const float2*)(orow + lane * 2);
  float ss = ov.x * ov.x + ov.y * ov.y;
#pragma unroll
  for (int mm = 32; mm >= 1; mm >>= 1) ss += __shfl_xor(ss, mm, 64);
  float scale = rsqrtf(ss * (1.f / 128.f) + EPSF);
  const float* gr = gpre + (size_t)m * TVv + h * 128 + lane * 2;
  float o0 = ov.x * scale * siluf(gr[0]);
  float o1 = ov.y * scale * siluf(gr[1]);
  *(uint*)(gof + (size_t)m * TVv + h * 128 + lane * 2) = pk2h(o0, o1);
}

// ---------------------------------------------------------------------------
extern "C" void kernel_launch(void* const* d_in, const int* in_sizes, int n_in,
                              void* d_out, int out_size, void* d_ws, size_t ws_size,
                              hipStream_t stream) {
  (void)in_sizes; (void)n_in; (void)out_size; (void)ws_size;
  const float* x       = (const float*)d_in[0];
  const float* w_q     = (const float*)d_in[1];
  const float* w_k     = (const float*)d_in[2];
  const float* w_v     = (const float*)d_in[3];
  const float* w_a     = (const float*)d_in[4];
  const float* w_b     = (const float*)d_in[5];
  const float* w_g     = (const float*)d_in[6];
  const float* w_out   = (const float*)d_in[7];
  const float* A_log   = (const float*)d_in[8];
  const float* dt_bias = (const float*)d_in[9];
  const float* qcw     = (const float*)d_in[10];
  const float* kcw     = (const float*)d_in[11];
  const float* vcw     = (const float*)d_in[12];

  float* ws      = (float*)d_ws;
  float* qkv_pre = ws;
  float* g_pre   = ws + 6291456;
  float* Cu      = ws + 9437184;
  float* abi     = ws + 15728640;

  ushort* xf    = (ushort*)Cu;
  ushort* wcat  = (ushort*)(Cu + 1572864);

  float* qc = Cu;
  float* kc = Cu + 1572864;
  float* vc = Cu + 3145728;

  ushort* woutf = (ushort*)Cu;

  float*  o   = qkv_pre;
  ushort* gof = (ushort*)(qkv_pre + 3145728);

  const int M = BB * TT;  // 2048
  dim3 blk(256);

  // 1) fp16 casts
  cast_f16_kernel<<<1536, blk, 0, stream>>>(x, xf);
  cast_w4_kernel<<<3456, blk, 0, stream>>>(w_q, w_k, w_v, w_g, wcat);

  // 2) fused qkv+g projection
  gemm_f16<<<dim3(NQKVG / 128, M / 128), blk, 0, stream>>>(
      xf, wcat, qkv_pre, g_pre, M, NQKVG, DD, CQKV, TVv, CQKV);

  // 3) gating coefficients
  gate_kernel<<<M, blk, 0, stream>>>(x, w_a, w_b, A_log, dt_bias, abi);

  // 4) conv + SiLU + L2 norm
  conv_silu_kernel<<<24576, blk, 0, stream>>>(qkv_pre, qcw, kcw, vcw, qc, kc, vc);

  // 5) chunked WY delta-rule scan (11 barriers/chunk)
  scan_chunked<<<48, blk, 0, stream>>>(qc, kc, vc, abi, o);

  // 6) cast w_out
  cast_f16_kernel<<<1152, blk, 0, stream>>>(w_out, woutf);

  // 7) RMS norm + SiLU gate
  rmsgate_kernel<<<6144, blk, 0, stream>>>(o, g_pre, gof);

  // 8) output projection
  gemm_f16<<<dim3(TVv / 128, M / 128), blk, 0, stream>>>(
      gof, woutf, (float*)d_out, (float*)d_out, M, TVv, DD, TVv, TVv, TVv);
}

// Round 17
// 276.849 us; speedup vs baseline: 1.2645x; 1.1811x over previous
//
#include <hip/hip_runtime.h>
#include <math.h>

#define BB 2
#define TT 1024
#define DD 1536
#define HH 12
#define TQK 768
#define TVv 1536
#define CQKV 3072
#define NQKVG 4608
#define EPSF 1e-6f
#define NBH (BB * HH)   // 24

typedef __attribute__((ext_vector_type(8))) _Float16 half8v;
typedef __attribute__((ext_vector_type(4))) float f32x4;

__device__ __forceinline__ float siluf(float x) { return x / (1.f + expf(-x)); }

__device__ __forceinline__ uint pk2h(float a, float b) {
  union { _Float16 h[2]; uint u; } p;
  p.h[0] = (_Float16)a; p.h[1] = (_Float16)b;
  return p.u;
}

// async global->LDS (GEMM staging)
__device__ __forceinline__ void gload16(const void* g, void* l) {
  __builtin_amdgcn_global_load_lds(
      (const __attribute__((address_space(1))) void*)g,
      (__attribute__((address_space(3))) void*)l, 16, 0, 0);
}

// ---------------------------------------------------------------------------
// fp16 MFMA GEMM (proven): C = X @ W^T -> f32.
// ---------------------------------------------------------------------------
__global__ __launch_bounds__(256) void gemm_f16(
    const ushort* __restrict__ X, const ushort* __restrict__ W,
    float* __restrict__ C1, float* __restrict__ C2,
    int M, int N, int K, int ldc1, int ldc2, int nsplit)
{
  __shared__ ushort Ah[128 * 64];
  __shared__ ushort Bh[128 * 64];
  const int tid  = threadIdx.x;
  const int lane = tid & 63;
  const int w    = tid >> 6;
  const int wr   = w >> 1, wc = w & 1;
  const int r0   = blockIdx.y * 128, c0 = blockIdx.x * 128;

  const int dr   = lane >> 3;
  const int slot = (lane & 7) ^ dr;

  f32x4 acc[4][4];
#pragma unroll
  for (int m = 0; m < 4; ++m)
#pragma unroll
    for (int n = 0; n < 4; ++n)
#pragma unroll
      for (int j = 0; j < 4; ++j) acc[m][n][j] = 0.f;

  for (int k0 = 0; k0 < K; k0 += 64) {
#pragma unroll
    for (int j = 0; j < 4; ++j) {
      const int row  = (w * 4 + j) * 8 + dr;
      const size_t xo = (size_t)(r0 + row) * K + k0 + slot * 8;
      const size_t wo = (size_t)(c0 + row) * K + k0 + slot * 8;
      const int ldso = (w * 4 + j) * 512;
      gload16(X + xo, Ah + ldso);
      gload16(W + wo, Bh + ldso);
    }
    __syncthreads();
#pragma unroll
    for (int kk = 0; kk < 2; ++kk) {
      const int kc8 = kk * 4 + (lane >> 4);
      const int sw  = (kc8 ^ (lane & 7)) << 3;
      half8v a[4], b[4];
#pragma unroll
      for (int m = 0; m < 4; ++m)
        a[m] = *(const half8v*)(Ah + (wr * 64 + m * 16 + (lane & 15)) * 64 + sw);
#pragma unroll
      for (int n = 0; n < 4; ++n)
        b[n] = *(const half8v*)(Bh + (wc * 64 + n * 16 + (lane & 15)) * 64 + sw);
#pragma unroll
      for (int m = 0; m < 4; ++m)
#pragma unroll
        for (int n = 0; n < 4; ++n)
          acc[m][n] = __builtin_amdgcn_mfma_f32_16x16x32_f16(a[m], b[n], acc[m][n], 0, 0, 0);
    }
    __syncthreads();
  }

  float* Cp; int ldc, cc0;
  if (c0 < nsplit) { Cp = C1; ldc = ldc1; cc0 = c0; }
  else             { Cp = C2; ldc = ldc2; cc0 = c0 - nsplit; }

  const int crow = (lane >> 4) * 4;
  const int ccol = lane & 15;
#pragma unroll
  for (int m = 0; m < 4; ++m)
#pragma unroll
    for (int j = 0; j < 4; ++j) {
      float* cp = Cp + (size_t)(r0 + wr * 64 + m * 16 + crow + j) * ldc + cc0 + wc * 64 + ccol;
#pragma unroll
      for (int n = 0; n < 4; ++n) cp[n * 16] = acc[m][n][j];
    }
}

// ---------------------------------------------------------------------------
// f32 -> fp16 casts.
// ---------------------------------------------------------------------------
__device__ __forceinline__ void cast8_store(const float* f, ushort* dst, size_t e)
{
  uint4 pk;
  pk.x = pk2h(f[0], f[1]); pk.y = pk2h(f[2], f[3]);
  pk.z = pk2h(f[4], f[5]); pk.w = pk2h(f[6], f[7]);
  *(uint4*)(dst + e) = pk;
}

__global__ void cast_f16_kernel(const float* __restrict__ src, ushort* __restrict__ dst)
{
  int cid = blockIdx.x * blockDim.x + threadIdx.x;
  size_t e = (size_t)cid * 8;
  float f[8];
  *(float4*)(f)     = *(const float4*)(src + e);
  *(float4*)(f + 4) = *(const float4*)(src + e + 4);
  cast8_store(f, dst, e);
}

__global__ void cast_w4_kernel(const float* __restrict__ wq, const float* __restrict__ wk,
                               const float* __restrict__ wv, const float* __restrict__ wg,
                               ushort* __restrict__ dst)
{
  int cid = blockIdx.x * blockDim.x + threadIdx.x;
  size_t e = (size_t)cid * 8;
  const float* src; size_t off;
  if (e < 1179648)      { src = wq; off = e; }
  else if (e < 2359296) { src = wk; off = e - 1179648; }
  else if (e < 4718592) { src = wv; off = e - 2359296; }
  else                  { src = wg; off = e - 4718592; }
  float f[8];
  *(float4*)(f)     = *(const float4*)(src + off);
  *(float4*)(f + 4) = *(const float4*)(src + off + 4);
  cast8_store(f, dst, e);
}

// ---------------------------------------------------------------------------
// Causal depthwise conv (K=4) + SiLU + fused L2-norm (q,k heads).
// ---------------------------------------------------------------------------
__global__ void conv_silu_kernel(
    const float* __restrict__ pre,
    const float* __restrict__ qw, const float* __restrict__ kw, const float* __restrict__ vw,
    float* __restrict__ qc, float* __restrict__ kc, float* __restrict__ vc)
{
  int idx = blockIdx.x * blockDim.x + threadIdx.x;
  int c  = idx % CQKV;
  int bt = idx / CQKV;
  int t  = bt % TT;
  int b  = bt / TT;

  const float* wp;
  if (c < TQK)          wp = qw + (size_t)c * 4;
  else if (c < 2 * TQK) wp = kw + (size_t)(c - TQK) * 4;
  else                  wp = vw + (size_t)(c - 2 * TQK) * 4;

  float s = 0.f;
#pragma unroll
  for (int j = 0; j < 4; ++j) {
    int ts = t - 3 + j;
    if (ts >= 0) s = fmaf(pre[(size_t)(b * TT + ts) * CQKV + c], wp[j], s);
  }
  s = siluf(s);

  if (c < 2 * TQK) {
    float ss = s * s;
#pragma unroll
    for (int m = 32; m >= 1; m >>= 1) ss += __shfl_xor(ss, m, 64);
    s = s / fmaxf(sqrtf(ss), EPSF);
  }

  if (c < TQK) {
    int h = c >> 6, d = c & 63;
    qc[((size_t)(b * HH + h) * TT + t) * 64 + d] = s;
  } else if (c < 2 * TQK) {
    int c2 = c - TQK; int h = c2 >> 6, d = c2 & 63;
    kc[((size_t)(b * HH + h) * TT + t) * 64 + d] = s;
  } else {
    int c2 = c - 2 * TQK; int h = c2 >> 7, d = c2 & 127;
    vc[((size_t)(b * HH + h) * TT + t) * 128 + d] = s;
  }
}

// ---------------------------------------------------------------------------
// Gating: block per row; writes interleaved (alpha,beta).
// ---------------------------------------------------------------------------
__global__ __launch_bounds__(256) void gate_kernel(
    const float* __restrict__ x, const float* __restrict__ w_a, const float* __restrict__ w_b,
    const float* __restrict__ A_log, const float* __restrict__ dt_bias,
    float* __restrict__ abi)
{
  const int m    = blockIdx.x;
  const int w    = threadIdx.x >> 6;
  const int lane = threadIdx.x & 63;
  const float* xr = x + (size_t)m * DD;
  float xv[24];
#pragma unroll
  for (int i = 0; i < 24; ++i) xv[i] = xr[lane + i * 64];
  const int b = m / TT, t = m % TT;
#pragma unroll
  for (int j = 0; j < 6; ++j) {
    int o = w * 6 + j;
    bool isA = o < HH;
    int h = isA ? o : o - HH;
    const float* wr = (isA ? w_a : w_b) + (size_t)h * DD;
    float s = 0.f;
#pragma unroll
    for (int i = 0; i < 24; ++i) s = fmaf(xv[i], wr[lane + i * 64], s);
#pragma unroll
    for (int mm = 32; mm >= 1; mm >>= 1) s += __shfl_xor(s, mm, 64);
    if (lane == 0) {
      size_t idx = ((size_t)(b * HH + h) * TT + t) * 2;
      if (isA) {
        float a  = s + dt_bias[h];
        float sp = (a > 20.f) ? a : log1pf(expf(a));
        abi[idx] = expf(-expf(A_log[h]) * sp);
      } else {
        abi[idx + 1] = 2.f / (1.f + expf(-s));
      }
    }
  }
}

// ---------------------------------------------------------------------------
// Shared 64x64 MFMA GEMM helper (verified R15/R16): C = X @ Y^T.
// ---------------------------------------------------------------------------
__device__ __forceinline__ void gemm64(
    const _Float16* XB, int xstr, const _Float16* YB, int ystr,
    int wr, int wc, int lane, int ksteps, int kpad, f32x4 acc[2][2])
{
#pragma unroll
  for (int m = 0; m < 2; ++m)
#pragma unroll
    for (int n = 0; n < 2; ++n)
#pragma unroll
      for (int j = 0; j < 4; ++j) acc[m][n][j] = 0.f;
#pragma unroll 4
  for (int kk = 0; kk < ksteps; ++kk) {
    const int koff = kk * 32 + ((kk >> 1) ? kpad : 0) + (lane >> 4) * 8;
    half8v a[2], b[2];
#pragma unroll
    for (int m = 0; m < 2; ++m)
      a[m] = *(const half8v*)(XB + (wr * 32 + m * 16 + (lane & 15)) * xstr + koff);
#pragma unroll
    for (int n = 0; n < 2; ++n)
      b[n] = *(const half8v*)(YB + (wc * 32 + n * 16 + (lane & 15)) * ystr + koff);
#pragma unroll
    for (int m = 0; m < 2; ++m)
#pragma unroll
      for (int n = 0; n < 2; ++n)
        acc[m][n] = __builtin_amdgcn_mfma_f32_16x16x32_f16(a[m], b[n], acc[m][n], 0, 0, 0);
  }
}

// ---------------------------------------------------------------------------
// Scan phase A (chunk-parallel, 384 blocks = c*24+bh): per chunk compute
// T = (I + mask(beta e^dg K K^T))^-1, then W = T diag(beta e^g) K (64x64) and
// Z = T V (64x128), stored f16 to global scratch. All chunk-local.
// ---------------------------------------------------------------------------
__global__ __launch_bounds__(256) void scan_phaseA(
    const float* __restrict__ kc, const float* __restrict__ vc,
    const float* __restrict__ abi, _Float16* __restrict__ Wg, _Float16* __restrict__ Zg)
{
  __shared__ _Float16 Kf[64 * 72];      // aliased as Tf after ph2
  __shared__ _Float16 KbT[64 * 72];     // [d][i] = betg_i k_i[d]
  __shared__ _Float16 VT[128 * 72];     // [v][t]
  __shared__ float    Af[64 * 67];
  __shared__ float    Tg[64 * 67];
  __shared__ float    tmpf[1088];
  __shared__ float    g_s[64], bet_s[64], betg_s[64];
  _Float16* Tf = Kf;

  const int unit = blockIdx.x;
  const int bh   = unit % NBH;
  const int c    = unit / NBH;
  const int c0   = c * 64;
  const int tid  = threadIdx.x;
  const int lane = tid & 63;
  const int w    = tid >> 6;
  const int wr   = w >> 1, wc = w & 1;

  // ph0: scalars [bar]
  if (tid < 64) {
    float2 ab = *(const float2*)(abi + ((size_t)bh * TT + c0 + tid) * 2);
    float gg = logf(ab.x);
#pragma unroll
    for (int off = 1; off < 64; off <<= 1) {
      float up = __shfl_up(gg, off, 64);
      if (tid >= off) gg += up;
    }
    g_s[tid]    = gg;
    bet_s[tid]  = ab.y;
    betg_s[tid] = ab.y * expf(gg);
  }
  __syncthreads();

  // ph1: build Kf, KbT, VT; zero Tg [bar]
  {
    const int t  = tid >> 2;
    const int dg = tid & 3;
    const float* krow = kc + ((size_t)bh * TT + c0 + t) * 64 + dg * 16;
    const float bg = betg_s[t];
#pragma unroll
    for (int q4 = 0; q4 < 4; ++q4) {
      float4 kv = *(const float4*)(krow + q4 * 4);
      const int d = dg * 16 + q4 * 4;
      const float kf[4] = {kv.x, kv.y, kv.z, kv.w};
#pragma unroll
      for (int e = 0; e < 4; ++e) {
        Kf[t * 72 + d + e]      = (_Float16)kf[e];
        KbT[(d + e) * 72 + t]   = (_Float16)(kf[e] * bg);
      }
    }
    const float* vrow = vc + ((size_t)bh * TT + c0 + t) * 128 + dg * 32;
#pragma unroll
    for (int q4 = 0; q4 < 8; ++q4) {
      float4 vv = *(const float4*)(vrow + q4 * 4);
      const int v = dg * 32 + q4 * 4;
      VT[(v + 0) * 72 + t] = (_Float16)vv.x;
      VT[(v + 1) * 72 + t] = (_Float16)vv.y;
      VT[(v + 2) * 72 + t] = (_Float16)vv.z;
      VT[(v + 3) * 72 + t] = (_Float16)vv.w;
    }
    for (int i = tid; i < 64 * 67; i += 256) Tg[i] = 0.f;
  }
  __syncthreads();

  // ph2: A = mask(beta e^dg K K^T) [bar]
  {
    f32x4 accA[2][2];
    gemm64(Kf, 72, Kf, 72, wr, wc, lane, 2, 0, accA);
#pragma unroll
    for (int m = 0; m < 2; ++m)
#pragma unroll
      for (int n = 0; n < 2; ++n)
#pragma unroll
        for (int j = 0; j < 4; ++j) {
          const int row = wr * 32 + m * 16 + (lane >> 4) * 4 + j;
          const int col = wc * 32 + n * 16 + (lane & 15);
          Af[row * 67 + col] =
              (col < row) ? bet_s[row] * expf(g_s[row] - g_s[col]) * accA[m][n][j] : 0.f;
        }
  }
  __syncthreads();

  // ph3a: 4 diagonal 16x16 inverses into Tg [bar]
  if (lane < 16) {
    const int R = w * 16;
    Tg[R * 67 + R + lane] = (lane == 0) ? 1.f : 0.f;
    for (int t = 1; t < 16; ++t) {
      float s = 0.f;
      for (int i = 0; i < t; ++i)
        s = fmaf(Af[(R + t) * 67 + R + i], Tg[(R + i) * 67 + R + lane], s);
      Tg[(R + t) * 67 + R + lane] = ((lane == t) ? 1.f : 0.f) - s;
    }
  }
  __syncthreads();
  // ph3b-1 [bar]
  {
    const int r = (tid >> 4) & 15, cx = tid & 15;
#pragma unroll
    for (int p = 0; p < 2; ++p) {
      float s = 0.f;
      for (int i = 0; i < 16; ++i)
        s = fmaf(Af[(p * 32 + 16 + r) * 67 + p * 32 + i],
                 Tg[(p * 32 + i) * 67 + p * 32 + cx], s);
      tmpf[p * 272 + r * 17 + cx] = s;
    }
  }
  __syncthreads();
  // ph3b-2 [bar]
  {
    const int r = (tid >> 4) & 15, cx = tid & 15;
#pragma unroll
    for (int p = 0; p < 2; ++p) {
      float s = 0.f;
      for (int i = 0; i < 16; ++i)
        s = fmaf(Tg[(p * 32 + 16 + r) * 67 + p * 32 + 16 + i],
                 tmpf[p * 272 + i * 17 + cx], s);
      Tg[(p * 32 + 16 + r) * 67 + p * 32 + cx] = -s;
    }
  }
  __syncthreads();
  // ph3c-1 [bar]
  {
#pragma unroll
    for (int rep = 0; rep < 4; ++rep) {
      const int idx = tid + rep * 256;
      const int r = idx >> 5, cx = idx & 31;
      float s = 0.f;
      for (int i = 0; i < 32; ++i)
        s = fmaf(Af[(32 + r) * 67 + i], Tg[i * 67 + cx], s);
      tmpf[r * 33 + cx] = s;
    }
  }
  __syncthreads();
  // ph3c-2 [bar]
  {
#pragma unroll
    for (int rep = 0; rep < 4; ++rep) {
      const int idx = tid + rep * 256;
      const int r = idx >> 5, cx = idx & 31;
      float s = 0.f;
      for (int i = 0; i < 32; ++i)
        s = fmaf(Tg[(32 + r) * 67 + 32 + i], tmpf[i * 33 + cx], s);
      Tg[(32 + r) * 67 + cx] = -s;
    }
  }
  __syncthreads();

  // ph4: cast Tg -> Tf (aliases Kf; Kf dead after ph2) [bar]
  {
    const int t = tid >> 2, qg = tid & 3;
#pragma unroll
    for (int e = 0; e < 16; ++e) {
      const int i = qg * 16 + e;
      Tf[t * 72 + i] = (_Float16)Tg[t * 67 + i];
    }
  }
  __syncthreads();

  // ph5: W = T @ KbT^T ; Z = T @ VT^T (two v-halves); store f16 global.
  {
    f32x4 accW[2][2];
    gemm64(Tf, 72, KbT, 72, wr, wc, lane, 2, 0, accW);
    _Float16* Wu = Wg + (size_t)unit * 4096;
#pragma unroll
    for (int m = 0; m < 2; ++m)
#pragma unroll
      for (int n = 0; n < 2; ++n)
#pragma unroll
        for (int j = 0; j < 4; ++j) {
          const int row = wr * 32 + m * 16 + (lane >> 4) * 4 + j;
          const int col = wc * 32 + n * 16 + (lane & 15);
          Wu[row * 64 + col] = (_Float16)accW[m][n][j];
        }
    _Float16* Zu = Zg + (size_t)unit * 8192;
#pragma unroll
    for (int H = 0; H < 2; ++H) {
      f32x4 accZ[2][2];
      gemm64(Tf, 72, VT + H * 64 * 72, 72, wr, wc, lane, 2, 0, accZ);
#pragma unroll
      for (int m = 0; m < 2; ++m)
#pragma unroll
        for (int n = 0; n < 2; ++n)
#pragma unroll
          for (int j = 0; j < 4; ++j) {
            const int row = wr * 32 + m * 16 + (lane >> 4) * 4 + j;
            const int col = wc * 32 + n * 16 + (lane & 15);
            Zu[row * 128 + H * 64 + col] = (_Float16)accZ[m][n][j];
          }
    }
  }
}

// ---------------------------------------------------------------------------
// Scan phase B (serial over 16 chunks, 24 blocks = bh): propagate S and emit O.
// Per chunk: rebuild Kf/Qf/KsT/Qg from qc/kc + scalars; load W,Z; then
//   P = mask(e^dg Q K^T); U = Z - W @ S0  (UT into Y2-right)
//   S = e^gC S + Ks^T @ U ; O = [Qg|P] @ [S0^T|U^T]^T  -> o
// ---------------------------------------------------------------------------
__global__ __launch_bounds__(256) void scan_phaseB(
    const float* __restrict__ qc, const float* __restrict__ kc,
    const float* __restrict__ abi, const _Float16* __restrict__ Wg,
    const _Float16* __restrict__ Zg, float* __restrict__ o)
{
  __shared__ float    Sf[128 * 65];     // S^T [v][d] f32 (persistent)
  __shared__ _Float16 Kf[64 * 72];
  __shared__ _Float16 Qf[64 * 72];
  __shared__ _Float16 KsT[64 * 72];     // [d][t]
  __shared__ _Float16 Wl[64 * 72];      // [t][d]
  __shared__ _Float16 Zl[64 * 136];     // [t][v]
  __shared__ _Float16 X2[64 * 144];     // [t][0:64]=Qg, [72:136]=P
  __shared__ _Float16 Y2[128 * 144];    // [v][0:64]=S^T f16, [72:136]=U^T
  __shared__ float    g_s[64], eg_s[64], eKs_s[64];
  __shared__ float    egC_s;

  const int bh   = blockIdx.x;
  const int b    = bh / HH, h = bh % HH;
  const int tid  = threadIdx.x;
  const int lane = tid & 63;
  const int w    = tid >> 6;
  const int wr   = w >> 1, wc = w & 1;

  for (int i = tid; i < 128 * 65; i += 256) Sf[i] = 0.f;
  __syncthreads();

  for (int c = 0; c < TT / 64; ++c) {
    const int c0   = c * 64;
    const size_t u = (size_t)(c * NBH + bh);

    // b0: scalars [bar]
    if (tid < 64) {
      float2 ab = *(const float2*)(abi + ((size_t)bh * TT + c0 + tid) * 2);
      float gg = logf(ab.x);
#pragma unroll
      for (int off = 1; off < 64; off <<= 1) {
        float up = __shfl_up(gg, off, 64);
        if (tid >= off) gg += up;
      }
      float gC = __shfl(gg, 63, 64);
      g_s[tid]   = gg;
      eg_s[tid]  = expf(gg);
      eKs_s[tid] = expf(gC - gg);
      if (tid == 0) egC_s = expf(gC);
    }
    __syncthreads();

    // b1: build Kf/Qf/KsT/X2-left; load Wl,Zl; cast Sf->Y2-left [bar]
    {
      const int t  = tid >> 2;
      const int dg = tid & 3;
      const float* krow = kc + ((size_t)bh * TT + c0 + t) * 64 + dg * 16;
      const float* qrow = qc + ((size_t)bh * TT + c0 + t) * 64 + dg * 16;
      const float ekt = eKs_s[t], egt = eg_s[t];
#pragma unroll
      for (int q4 = 0; q4 < 4; ++q4) {
        float4 kv = *(const float4*)(krow + q4 * 4);
        float4 qv = *(const float4*)(qrow + q4 * 4);
        const int d = dg * 16 + q4 * 4;
        const float kf[4] = {kv.x, kv.y, kv.z, kv.w};
        const float qf[4] = {qv.x, qv.y, qv.z, qv.w};
#pragma unroll
        for (int e = 0; e < 4; ++e) {
          Kf[t * 72 + d + e]    = (_Float16)kf[e];
          KsT[(d + e) * 72 + t] = (_Float16)(kf[e] * ekt);
          Qf[t * 72 + d + e]    = (_Float16)qf[e];
          X2[t * 144 + d + e]   = (_Float16)(qf[e] * egt);
        }
      }
      // Wl: [t][64] from Wg (stride 72 in LDS)
      {
        const int seg = tid & 3;
        const ushort* src = (const ushort*)(Wg + u * 4096) + t * 64 + seg * 16;
        *(uint4*)((ushort*)Wl + t * 72 + seg * 16)     = *(const uint4*)(src);
        *(uint4*)((ushort*)Wl + t * 72 + seg * 16 + 8) = *(const uint4*)(src + 8);
      }
      // Zl: [t][128] from Zg (stride 136)
      {
        const int seg = tid & 3;
        const ushort* src = (const ushort*)(Zg + u * 8192) + t * 128 + seg * 32;
#pragma unroll
        for (int q = 0; q < 4; ++q)
          *(uint4*)((ushort*)Zl + t * 136 + seg * 32 + q * 8) = *(const uint4*)(src + q * 8);
      }
      // Sf -> Y2-left (f16)
      {
        const int v = tid >> 1, half = tid & 1;
#pragma unroll
        for (int e = 0; e < 32; ++e)
          Y2[v * 144 + half * 32 + e] = (_Float16)Sf[v * 65 + half * 32 + e];
      }
    }
    __syncthreads();

    // b2: P = mask(e^dg Q K^T) -> X2-right ; U = Z - W@S0 -> Y2-right [bar]
    {
      f32x4 accP[2][2];
      gemm64(Qf, 72, Kf, 72, wr, wc, lane, 2, 0, accP);
#pragma unroll
      for (int m = 0; m < 2; ++m)
#pragma unroll
        for (int n = 0; n < 2; ++n)
#pragma unroll
          for (int j = 0; j < 4; ++j) {
            const int row = wr * 32 + m * 16 + (lane >> 4) * 4 + j;
            const int col = wc * 32 + n * 16 + (lane & 15);
            X2[row * 144 + 72 + col] =
                (col <= row) ? (_Float16)(expf(g_s[row] - g_s[col]) * accP[m][n][j])
                             : (_Float16)0.f;
          }
#pragma unroll
      for (int H = 0; H < 2; ++H) {
        f32x4 accU[2][2];
        gemm64(Wl, 72, Y2 + H * 64 * 144, 144, wr, wc, lane, 2, 0, accU);
#pragma unroll
        for (int m = 0; m < 2; ++m)
#pragma unroll
          for (int n = 0; n < 2; ++n)
#pragma unroll
            for (int j = 0; j < 4; ++j) {
              const int row = wr * 32 + m * 16 + (lane >> 4) * 4 + j;  // t
              const int col = wc * 32 + n * 16 + (lane & 15);          // v in half
              const float uval =
                  (float)Zl[row * 136 + H * 64 + col] - accU[m][n][j];
              Y2[(H * 64 + col) * 144 + 72 + row] = (_Float16)uval;
            }
      }
    }
    __syncthreads();

    // b3: S = egC*S + Ks^T@U ; O = [Qg|P]@[S0^T|U^T]^T -> o [bar]
    {
      const float egC = egC_s;
#pragma unroll
      for (int H = 0; H < 2; ++H) {
        f32x4 accS[2][2], accO[2][2];
        gemm64(KsT, 72, Y2 + H * 64 * 144 + 72, 144, wr, wc, lane, 2, 0, accS);
        gemm64(X2, 144, Y2 + H * 64 * 144, 144, wr, wc, lane, 4, 8, accO);
#pragma unroll
        for (int m = 0; m < 2; ++m)
#pragma unroll
          for (int n = 0; n < 2; ++n)
#pragma unroll
            for (int j = 0; j < 4; ++j) {
              const int row = wr * 32 + m * 16 + (lane >> 4) * 4 + j;  // d (S) / t (O)
              const int col = wc * 32 + n * 16 + (lane & 15);          // v in half
              Sf[(H * 64 + col) * 65 + row] = egC * Sf[(H * 64 + col) * 65 + row] + accS[m][n][j];
              o[(((size_t)b * TT + c0 + row) * HH + h) * 128 + H * 64 + col] = accO[m][n][j];
            }
      }
    }
    __syncthreads();
  }
}

// ---------------------------------------------------------------------------
// RMS norm over 128 + SiLU gate; emits fp16 for the final GEMM.
// ---------------------------------------------------------------------------
__global__ void rmsgate_kernel(const float* __restrict__ o, const float* __restrict__ gpre,
                               ushort* __restrict__ gof)
{
  int gid  = blockIdx.x * blockDim.x + threadIdx.x;
  int wid  = gid >> 6;
  int lane = threadIdx.x & 63;
  if (wid >= BB * TT * HH) return;
  int h = wid % HH;
  int m = wid / HH;
  const float* orow = o + (size_t)wid * 128;
  float2 ov = *(const float2*)(orow + lane * 2);
  float ss = ov.x * ov.x + ov.y * ov.y;
#pragma unroll
  for (int mm = 32; mm >= 1; mm >>= 1) ss += __shfl_xor(ss, mm, 64);
  float scale = rsqrtf(ss * (1.f / 128.f) + EPSF);
  const float* gr = gpre + (size_t)m * TVv + h * 128 + lane * 2;
  float o0 = ov.x * scale * siluf(gr[0]);
  float o1 = ov.y * scale * siluf(gr[1]);
  *(uint*)(gof + (size_t)m * TVv + h * 128 + lane * 2) = pk2h(o0, o1);
}

// ---------------------------------------------------------------------------
extern "C" void kernel_launch(void* const* d_in, const int* in_sizes, int n_in,
                              void* d_out, int out_size, void* d_ws, size_t ws_size,
                              hipStream_t stream) {
  (void)in_sizes; (void)n_in; (void)out_size; (void)ws_size;
  const float* x       = (const float*)d_in[0];
  const float* w_q     = (const float*)d_in[1];
  const float* w_k     = (const float*)d_in[2];
  const float* w_v     = (const float*)d_in[3];
  const float* w_a     = (const float*)d_in[4];
  const float* w_b     = (const float*)d_in[5];
  const float* w_g     = (const float*)d_in[6];
  const float* w_out   = (const float*)d_in[7];
  const float* A_log   = (const float*)d_in[8];
  const float* dt_bias = (const float*)d_in[9];
  const float* qcw     = (const float*)d_in[10];
  const float* kcw     = (const float*)d_in[11];
  const float* vcw     = (const float*)d_in[12];

  // Workspace (63.11 MB proven footprint):
  //  [0..3145728)            o (f32)
  //  [3145728..6291456)      during scan: Wg (786432 f) + Zg (1572864 f);
  //                          after scan: gof (ushort, 1572864 f)
  //  [6291456..9437184)      g_pre
  //  [9437184..15728640)     Cu: phase1 xf+wcat, phase2 qc/kc/vc, phase3 woutf
  //  [15728640..15777792)    abi
  float* ws      = (float*)d_ws;
  float* qkv_pre = ws;
  float* g_pre   = ws + 6291456;
  float* Cu      = ws + 9437184;
  float* abi     = ws + 15728640;

  ushort* xf    = (ushort*)Cu;
  ushort* wcat  = (ushort*)(Cu + 1572864);

  float* qc = Cu;
  float* kc = Cu + 1572864;
  float* vc = Cu + 3145728;

  ushort* woutf = (ushort*)Cu;

  float*    o   = qkv_pre;
  ushort*   gof = (ushort*)(qkv_pre + 3145728);
  _Float16* Wg  = (_Float16*)(qkv_pre + 3145728);
  _Float16* Zg  = (_Float16*)(qkv_pre + 3932160);

  const int M = BB * TT;  // 2048
  dim3 blk(256);

  // 1) fp16 casts
  cast_f16_kernel<<<1536, blk, 0, stream>>>(x, xf);
  cast_w4_kernel<<<3456, blk, 0, stream>>>(w_q, w_k, w_v, w_g, wcat);

  // 2) fused qkv+g projection
  gemm_f16<<<dim3(NQKVG / 128, M / 128), blk, 0, stream>>>(
      xf, wcat, qkv_pre, g_pre, M, NQKVG, DD, CQKV, TVv, CQKV);

  // 3) gating coefficients
  gate_kernel<<<M, blk, 0, stream>>>(x, w_a, w_b, A_log, dt_bias, abi);

  // 4) conv + SiLU + L2 norm
  conv_silu_kernel<<<24576, blk, 0, stream>>>(qkv_pre, qcw, kcw, vcw, qc, kc, vc);

  // 5) scan: chunk-parallel phase A, thin serial phase B
  scan_phaseA<<<16 * NBH, blk, 0, stream>>>(kc, vc, abi, Wg, Zg);
  scan_phaseB<<<NBH, blk, 0, stream>>>(qc, kc, abi, Wg, Zg, o);

  // 6) cast w_out (overwrites qc)
  cast_f16_kernel<<<1152, blk, 0, stream>>>(w_out, woutf);

  // 7) RMS norm + SiLU gate (gof overwrites dead Wg/Zg scratch)
  rmsgate_kernel<<<6144, blk, 0, stream>>>(o, g_pre, gof);

  // 8) output projection
  gemm_f16<<<dim3(TVv / 128, M / 128), blk, 0, stream>>>(
      gof, woutf, (float*)d_out, (float*)d_out, M, TVv, DD, TVv, TVv, TVv);
}

// Round 18
// 238.836 us; speedup vs baseline: 1.4658x; 1.1592x over previous
//
#include <hip/hip_runtime.h>
#include <math.h>

#define BB 2
#define TT 1024
#define DD 1536
#define HH 12
#define TQK 768
#define TVv 1536
#define CQKV 3072
#define NQKVG 4608
#define EPSF 1e-6f
#define NBH (BB * HH)   // 24

typedef __attribute__((ext_vector_type(8))) _Float16 half8v;
typedef __attribute__((ext_vector_type(4))) float f32x4;

__device__ __forceinline__ float siluf(float x) { return x / (1.f + expf(-x)); }

__device__ __forceinline__ uint pk2h(float a, float b) {
  union { _Float16 h[2]; uint u; } p;
  p.h[0] = (_Float16)a; p.h[1] = (_Float16)b;
  return p.u;
}

// async global->LDS (GEMM staging)
__device__ __forceinline__ void gload16(const void* g, void* l) {
  __builtin_amdgcn_global_load_lds(
      (const __attribute__((address_space(1))) void*)g,
      (__attribute__((address_space(3))) void*)l, 16, 0, 0);
}

// ---------------------------------------------------------------------------
// fp16 MFMA GEMM (proven): C = X @ W^T -> f32.
// ---------------------------------------------------------------------------
__global__ __launch_bounds__(256) void gemm_f16(
    const ushort* __restrict__ X, const ushort* __restrict__ W,
    float* __restrict__ C1, float* __restrict__ C2,
    int M, int N, int K, int ldc1, int ldc2, int nsplit)
{
  __shared__ ushort Ah[128 * 64];
  __shared__ ushort Bh[128 * 64];
  const int tid  = threadIdx.x;
  const int lane = tid & 63;
  const int w    = tid >> 6;
  const int wr   = w >> 1, wc = w & 1;
  const int r0   = blockIdx.y * 128, c0 = blockIdx.x * 128;

  const int dr   = lane >> 3;
  const int slot = (lane & 7) ^ dr;

  f32x4 acc[4][4];
#pragma unroll
  for (int m = 0; m < 4; ++m)
#pragma unroll
    for (int n = 0; n < 4; ++n)
#pragma unroll
      for (int j = 0; j < 4; ++j) acc[m][n][j] = 0.f;

  for (int k0 = 0; k0 < K; k0 += 64) {
#pragma unroll
    for (int j = 0; j < 4; ++j) {
      const int row  = (w * 4 + j) * 8 + dr;
      const size_t xo = (size_t)(r0 + row) * K + k0 + slot * 8;
      const size_t wo = (size_t)(c0 + row) * K + k0 + slot * 8;
      const int ldso = (w * 4 + j) * 512;
      gload16(X + xo, Ah + ldso);
      gload16(W + wo, Bh + ldso);
    }
    __syncthreads();
#pragma unroll
    for (int kk = 0; kk < 2; ++kk) {
      const int kc8 = kk * 4 + (lane >> 4);
      const int sw  = (kc8 ^ (lane & 7)) << 3;
      half8v a[4], b[4];
#pragma unroll
      for (int m = 0; m < 4; ++m)
        a[m] = *(const half8v*)(Ah + (wr * 64 + m * 16 + (lane & 15)) * 64 + sw);
#pragma unroll
      for (int n = 0; n < 4; ++n)
        b[n] = *(const half8v*)(Bh + (wc * 64 + n * 16 + (lane & 15)) * 64 + sw);
#pragma unroll
      for (int m = 0; m < 4; ++m)
#pragma unroll
        for (int n = 0; n < 4; ++n)
          acc[m][n] = __builtin_amdgcn_mfma_f32_16x16x32_f16(a[m], b[n], acc[m][n], 0, 0, 0);
    }
    __syncthreads();
  }

  float* Cp; int ldc, cc0;
  if (c0 < nsplit) { Cp = C1; ldc = ldc1; cc0 = c0; }
  else             { Cp = C2; ldc = ldc2; cc0 = c0 - nsplit; }

  const int crow = (lane >> 4) * 4;
  const int ccol = lane & 15;
#pragma unroll
  for (int m = 0; m < 4; ++m)
#pragma unroll
    for (int j = 0; j < 4; ++j) {
      float* cp = Cp + (size_t)(r0 + wr * 64 + m * 16 + crow + j) * ldc + cc0 + wc * 64 + ccol;
#pragma unroll
      for (int n = 0; n < 4; ++n) cp[n * 16] = acc[m][n][j];
    }
}

// ---------------------------------------------------------------------------
// f32 -> fp16 casts.
// ---------------------------------------------------------------------------
__device__ __forceinline__ void cast8_store(const float* f, ushort* dst, size_t e)
{
  uint4 pk;
  pk.x = pk2h(f[0], f[1]); pk.y = pk2h(f[2], f[3]);
  pk.z = pk2h(f[4], f[5]); pk.w = pk2h(f[6], f[7]);
  *(uint4*)(dst + e) = pk;
}

__global__ void cast_f16_kernel(const float* __restrict__ src, ushort* __restrict__ dst)
{
  int cid = blockIdx.x * blockDim.x + threadIdx.x;
  size_t e = (size_t)cid * 8;
  float f[8];
  *(float4*)(f)     = *(const float4*)(src + e);
  *(float4*)(f + 4) = *(const float4*)(src + e + 4);
  cast8_store(f, dst, e);
}

__global__ void cast_w4_kernel(const float* __restrict__ wq, const float* __restrict__ wk,
                               const float* __restrict__ wv, const float* __restrict__ wg,
                               ushort* __restrict__ dst)
{
  int cid = blockIdx.x * blockDim.x + threadIdx.x;
  size_t e = (size_t)cid * 8;
  const float* src; size_t off;
  if (e < 1179648)      { src = wq; off = e; }
  else if (e < 2359296) { src = wk; off = e - 1179648; }
  else if (e < 4718592) { src = wv; off = e - 2359296; }
  else                  { src = wg; off = e - 4718592; }
  float f[8];
  *(float4*)(f)     = *(const float4*)(src + off);
  *(float4*)(f + 4) = *(const float4*)(src + off + 4);
  cast8_store(f, dst, e);
}

// ---------------------------------------------------------------------------
// Causal depthwise conv (K=4) + SiLU + fused L2-norm (q,k heads).
// ---------------------------------------------------------------------------
__global__ void conv_silu_kernel(
    const float* __restrict__ pre,
    const float* __restrict__ qw, const float* __restrict__ kw, const float* __restrict__ vw,
    float* __restrict__ qc, float* __restrict__ kc, float* __restrict__ vc)
{
  int idx = blockIdx.x * blockDim.x + threadIdx.x;
  int c  = idx % CQKV;
  int bt = idx / CQKV;
  int t  = bt % TT;
  int b  = bt / TT;

  const float* wp;
  if (c < TQK)          wp = qw + (size_t)c * 4;
  else if (c < 2 * TQK) wp = kw + (size_t)(c - TQK) * 4;
  else                  wp = vw + (size_t)(c - 2 * TQK) * 4;

  float s = 0.f;
#pragma unroll
  for (int j = 0; j < 4; ++j) {
    int ts = t - 3 + j;
    if (ts >= 0) s = fmaf(pre[(size_t)(b * TT + ts) * CQKV + c], wp[j], s);
  }
  s = siluf(s);

  if (c < 2 * TQK) {
    float ss = s * s;
#pragma unroll
    for (int m = 32; m >= 1; m >>= 1) ss += __shfl_xor(ss, m, 64);
    s = s / fmaxf(sqrtf(ss), EPSF);
  }

  if (c < TQK) {
    int h = c >> 6, d = c & 63;
    qc[((size_t)(b * HH + h) * TT + t) * 64 + d] = s;
  } else if (c < 2 * TQK) {
    int c2 = c - TQK; int h = c2 >> 6, d = c2 & 63;
    kc[((size_t)(b * HH + h) * TT + t) * 64 + d] = s;
  } else {
    int c2 = c - 2 * TQK; int h = c2 >> 7, d = c2 & 127;
    vc[((size_t)(b * HH + h) * TT + t) * 128 + d] = s;
  }
}

// ---------------------------------------------------------------------------
// Gating: block per row; writes interleaved (alpha,beta).
// ---------------------------------------------------------------------------
__global__ __launch_bounds__(256) void gate_kernel(
    const float* __restrict__ x, const float* __restrict__ w_a, const float* __restrict__ w_b,
    const float* __restrict__ A_log, const float* __restrict__ dt_bias,
    float* __restrict__ abi)
{
  const int m    = blockIdx.x;
  const int w    = threadIdx.x >> 6;
  const int lane = threadIdx.x & 63;
  const float* xr = x + (size_t)m * DD;
  float xv[24];
#pragma unroll
  for (int i = 0; i < 24; ++i) xv[i] = xr[lane + i * 64];
  const int b = m / TT, t = m % TT;
#pragma unroll
  for (int j = 0; j < 6; ++j) {
    int o = w * 6 + j;
    bool isA = o < HH;
    int h = isA ? o : o - HH;
    const float* wr = (isA ? w_a : w_b) + (size_t)h * DD;
    float s = 0.f;
#pragma unroll
    for (int i = 0; i < 24; ++i) s = fmaf(xv[i], wr[lane + i * 64], s);
#pragma unroll
    for (int mm = 32; mm >= 1; mm >>= 1) s += __shfl_xor(s, mm, 64);
    if (lane == 0) {
      size_t idx = ((size_t)(b * HH + h) * TT + t) * 2;
      if (isA) {
        float a  = s + dt_bias[h];
        float sp = (a > 20.f) ? a : log1pf(expf(a));
        abi[idx] = expf(-expf(A_log[h]) * sp);
      } else {
        abi[idx + 1] = 2.f / (1.f + expf(-s));
      }
    }
  }
}

// ---------------------------------------------------------------------------
// Shared 64x64 MFMA GEMM helper (verified): C = X @ Y^T.
// ---------------------------------------------------------------------------
__device__ __forceinline__ void gemm64(
    const _Float16* XB, int xstr, const _Float16* YB, int ystr,
    int wr, int wc, int lane, int ksteps, int kpad, f32x4 acc[2][2])
{
#pragma unroll
  for (int m = 0; m < 2; ++m)
#pragma unroll
    for (int n = 0; n < 2; ++n)
#pragma unroll
      for (int j = 0; j < 4; ++j) acc[m][n][j] = 0.f;
#pragma unroll 4
  for (int kk = 0; kk < ksteps; ++kk) {
    const int koff = kk * 32 + ((kk >> 1) ? kpad : 0) + (lane >> 4) * 8;
    half8v a[2], b[2];
#pragma unroll
    for (int m = 0; m < 2; ++m)
      a[m] = *(const half8v*)(XB + (wr * 32 + m * 16 + (lane & 15)) * xstr + koff);
#pragma unroll
    for (int n = 0; n < 2; ++n)
      b[n] = *(const half8v*)(YB + (wc * 32 + n * 16 + (lane & 15)) * ystr + koff);
#pragma unroll
    for (int m = 0; m < 2; ++m)
#pragma unroll
      for (int n = 0; n < 2; ++n)
        acc[m][n] = __builtin_amdgcn_mfma_f32_16x16x32_f16(a[m], b[n], acc[m][n], 0, 0, 0);
  }
}

// ---------------------------------------------------------------------------
// Scan phase A (chunk-parallel, 384 blocks): per chunk compute and store f16:
//   W = T diag(beta e^g) K   (4096)     P  = mask(e^dg Q K^T)  (4096)
//   Qg = e^g q               (4096)     KsT[d][t] = e^{gC-g_t} k (4096)
//   Z = T V                  (8192)     egCg[unit] = e^{gC}
// Unit scratch = 24576 f16 (48KB); T = (I + mask(beta e^dg KK^T))^-1.
// ---------------------------------------------------------------------------
__global__ __launch_bounds__(256) void scan_phaseA(
    const float* __restrict__ qc, const float* __restrict__ kc, const float* __restrict__ vc,
    const float* __restrict__ abi, _Float16* __restrict__ SA, float* __restrict__ egCg)
{
  __shared__ _Float16 Kf[64 * 72];      // aliased as Tf after ph2
  __shared__ _Float16 Qf[64 * 72];
  __shared__ _Float16 KbT[64 * 72];     // [d][i] = betg_i k_i[d]
  __shared__ _Float16 VT[128 * 72];     // [v][t]
  __shared__ float    Af[64 * 67];
  __shared__ float    Tg[64 * 67];
  __shared__ float    tmpf[1088];
  __shared__ float    g_s[64], bet_s[64], betg_s[64], eg_s[64], eKs_s[64];
  _Float16* Tf = Kf;

  const int unit = blockIdx.x;
  const int bh   = unit % NBH;
  const int c    = unit / NBH;
  const int c0   = c * 64;
  const int tid  = threadIdx.x;
  const int lane = tid & 63;
  const int w    = tid >> 6;
  const int wr   = w >> 1, wc = w & 1;

  _Float16* SAu = SA + (size_t)unit * 24576;

  // ph0: scalars [bar]
  if (tid < 64) {
    float2 ab = *(const float2*)(abi + ((size_t)bh * TT + c0 + tid) * 2);
    float gg = logf(ab.x);
#pragma unroll
    for (int off = 1; off < 64; off <<= 1) {
      float up = __shfl_up(gg, off, 64);
      if (tid >= off) gg += up;
    }
    float gC = __shfl(gg, 63, 64);
    g_s[tid]    = gg;
    bet_s[tid]  = ab.y;
    betg_s[tid] = ab.y * expf(gg);
    eg_s[tid]   = expf(gg);
    eKs_s[tid]  = expf(gC - gg);
    if (tid == 0) egCg[unit] = expf(gC);
  }
  __syncthreads();

  // ph1: build Kf, KbT, Qf, VT; store Qg, KsT scratch; zero Tg [bar]
  {
    const int t  = tid >> 2;
    const int dg = tid & 3;
    const float* krow = kc + ((size_t)bh * TT + c0 + t) * 64 + dg * 16;
    const float* qrow = qc + ((size_t)bh * TT + c0 + t) * 64 + dg * 16;
    const float bg = betg_s[t], egt = eg_s[t], ekt = eKs_s[t];
#pragma unroll
    for (int q4 = 0; q4 < 4; ++q4) {
      float4 kv = *(const float4*)(krow + q4 * 4);
      float4 qv = *(const float4*)(qrow + q4 * 4);
      const int d = dg * 16 + q4 * 4;
      const float kf[4] = {kv.x, kv.y, kv.z, kv.w};
      const float qf[4] = {qv.x, qv.y, qv.z, qv.w};
#pragma unroll
      for (int e = 0; e < 4; ++e) {
        Kf[t * 72 + d + e]        = (_Float16)kf[e];
        KbT[(d + e) * 72 + t]     = (_Float16)(kf[e] * bg);
        Qf[t * 72 + d + e]        = (_Float16)qf[e];
        SAu[8192 + t * 64 + d + e]  = (_Float16)(qf[e] * egt);   // Qg
        SAu[12288 + (d + e) * 64 + t] = (_Float16)(kf[e] * ekt); // KsT [d][t]
      }
    }
    const float* vrow = vc + ((size_t)bh * TT + c0 + t) * 128 + dg * 32;
#pragma unroll
    for (int q4 = 0; q4 < 8; ++q4) {
      float4 vv = *(const float4*)(vrow + q4 * 4);
      const int v = dg * 32 + q4 * 4;
      VT[(v + 0) * 72 + t] = (_Float16)vv.x;
      VT[(v + 1) * 72 + t] = (_Float16)vv.y;
      VT[(v + 2) * 72 + t] = (_Float16)vv.z;
      VT[(v + 3) * 72 + t] = (_Float16)vv.w;
    }
    for (int i = tid; i < 64 * 67; i += 256) Tg[i] = 0.f;
  }
  __syncthreads();

  // ph2: A = mask(beta e^dg K K^T) -> Af ; P = mask(e^dg Q K^T) -> scratch [bar]
  {
    f32x4 accA[2][2], accP[2][2];
    gemm64(Kf, 72, Kf, 72, wr, wc, lane, 2, 0, accA);
    gemm64(Qf, 72, Kf, 72, wr, wc, lane, 2, 0, accP);
#pragma unroll
    for (int m = 0; m < 2; ++m)
#pragma unroll
      for (int n = 0; n < 2; ++n)
#pragma unroll
        for (int j = 0; j < 4; ++j) {
          const int row = wr * 32 + m * 16 + (lane >> 4) * 4 + j;
          const int col = wc * 32 + n * 16 + (lane & 15);
          const float eg = expf(g_s[row] - g_s[col]);
          Af[row * 67 + col] = (col < row) ? bet_s[row] * eg * accA[m][n][j] : 0.f;
          SAu[4096 + row * 64 + col] =
              (col <= row) ? (_Float16)(eg * accP[m][n][j]) : (_Float16)0.f;
        }
  }
  __syncthreads();

  // ph3a: 4 diagonal 16x16 inverses into Tg [bar]
  if (lane < 16) {
    const int R = w * 16;
    Tg[R * 67 + R + lane] = (lane == 0) ? 1.f : 0.f;
    for (int t = 1; t < 16; ++t) {
      float s = 0.f;
      for (int i = 0; i < t; ++i)
        s = fmaf(Af[(R + t) * 67 + R + i], Tg[(R + i) * 67 + R + lane], s);
      Tg[(R + t) * 67 + R + lane] = ((lane == t) ? 1.f : 0.f) - s;
    }
  }
  __syncthreads();
  // ph3b-1 [bar]
  {
    const int r = (tid >> 4) & 15, cx = tid & 15;
#pragma unroll
    for (int p = 0; p < 2; ++p) {
      float s = 0.f;
      for (int i = 0; i < 16; ++i)
        s = fmaf(Af[(p * 32 + 16 + r) * 67 + p * 32 + i],
                 Tg[(p * 32 + i) * 67 + p * 32 + cx], s);
      tmpf[p * 272 + r * 17 + cx] = s;
    }
  }
  __syncthreads();
  // ph3b-2 [bar]
  {
    const int r = (tid >> 4) & 15, cx = tid & 15;
#pragma unroll
    for (int p = 0; p < 2; ++p) {
      float s = 0.f;
      for (int i = 0; i < 16; ++i)
        s = fmaf(Tg[(p * 32 + 16 + r) * 67 + p * 32 + 16 + i],
                 tmpf[p * 272 + i * 17 + cx], s);
      Tg[(p * 32 + 16 + r) * 67 + p * 32 + cx] = -s;
    }
  }
  __syncthreads();
  // ph3c-1 [bar]
  {
#pragma unroll
    for (int rep = 0; rep < 4; ++rep) {
      const int idx = tid + rep * 256;
      const int r = idx >> 5, cx = idx & 31;
      float s = 0.f;
      for (int i = 0; i < 32; ++i)
        s = fmaf(Af[(32 + r) * 67 + i], Tg[i * 67 + cx], s);
      tmpf[r * 33 + cx] = s;
    }
  }
  __syncthreads();
  // ph3c-2 [bar]
  {
#pragma unroll
    for (int rep = 0; rep < 4; ++rep) {
      const int idx = tid + rep * 256;
      const int r = idx >> 5, cx = idx & 31;
      float s = 0.f;
      for (int i = 0; i < 32; ++i)
        s = fmaf(Tg[(32 + r) * 67 + 32 + i], tmpf[i * 33 + cx], s);
      Tg[(32 + r) * 67 + cx] = -s;
    }
  }
  __syncthreads();

  // ph4: cast Tg -> Tf (aliases Kf; Kf dead after ph2) [bar]
  {
    const int t = tid >> 2, qg = tid & 3;
#pragma unroll
    for (int e = 0; e < 16; ++e) {
      const int i = qg * 16 + e;
      Tf[t * 72 + i] = (_Float16)Tg[t * 67 + i];
    }
  }
  __syncthreads();

  // ph5: W = T @ KbT^T -> scratch ; Z = T @ VT^T (two halves) -> scratch
  {
    f32x4 accW[2][2];
    gemm64(Tf, 72, KbT, 72, wr, wc, lane, 2, 0, accW);
#pragma unroll
    for (int m = 0; m < 2; ++m)
#pragma unroll
      for (int n = 0; n < 2; ++n)
#pragma unroll
        for (int j = 0; j < 4; ++j) {
          const int row = wr * 32 + m * 16 + (lane >> 4) * 4 + j;
          const int col = wc * 32 + n * 16 + (lane & 15);
          SAu[row * 64 + col] = (_Float16)accW[m][n][j];
        }
#pragma unroll
    for (int H = 0; H < 2; ++H) {
      f32x4 accZ[2][2];
      gemm64(Tf, 72, VT + H * 64 * 72, 72, wr, wc, lane, 2, 0, accZ);
#pragma unroll
      for (int m = 0; m < 2; ++m)
#pragma unroll
        for (int n = 0; n < 2; ++n)
#pragma unroll
          for (int j = 0; j < 4; ++j) {
            const int row = wr * 32 + m * 16 + (lane >> 4) * 4 + j;
            const int col = wc * 32 + n * 16 + (lane & 15);
            SAu[16384 + row * 128 + H * 64 + col] = (_Float16)accZ[m][n][j];
          }
    }
  }
}

// ---------------------------------------------------------------------------
// Scan phase B (serial over 16 chunks; 48 blocks = bh x 2 v-halves): pure
// scratch consumer. Per chunk: load W,P,Qg,KsT,Z-half (40KB f16) + egC;
//   U = Z - W @ S0 ; S = e^gC S + KsT @ U ; O = [Qg|P] @ [S0^T|U^T]^T.
// 3 barriers/chunk, no expf/logf, no K/Q rebuild.
// ---------------------------------------------------------------------------
__global__ __launch_bounds__(256) void scan_phaseB(
    const _Float16* __restrict__ SA, const float* __restrict__ egCg,
    float* __restrict__ o)
{
  __shared__ float    Sf[64 * 65];      // S^T half [v][d] f32 (persistent)
  __shared__ _Float16 Wl[64 * 72];      // [t][d]
  __shared__ _Float16 KsTl[64 * 72];    // [d][t]
  __shared__ _Float16 Zl[64 * 72];      // [t][v-half]
  __shared__ _Float16 X2[64 * 144];     // [t][0:64]=Qg, [72:136]=P
  __shared__ _Float16 Y2[64 * 144];     // [v][0:64]=S0^T f16, [72:136]=U^T

  const int blk  = blockIdx.x;
  const int bh   = blk % NBH;
  const int H    = blk / NBH;           // 0..1 (v half)
  const int b    = bh / HH, h = bh % HH;
  const int tid  = threadIdx.x;
  const int lane = tid & 63;
  const int w    = tid >> 6;
  const int wr   = w >> 1, wc = w & 1;

  for (int i = tid; i < 64 * 65; i += 256) Sf[i] = 0.f;
  __syncthreads();

  for (int c = 0; c < TT / 64; ++c) {
    const int c0   = c * 64;
    const size_t u = (size_t)(c * NBH + bh);
    const ushort* base = (const ushort*)(SA + u * 24576);
    const float egC = egCg[u];

    // b1: load 5 matrices to LDS; cast Sf -> Y2-left [bar]
    {
#pragma unroll
      for (int r = 0; r < 2; ++r) {
        const int idx = tid + r * 256;       // 0..511
        const int row = idx >> 3, c8 = idx & 7;
        *(uint4*)((ushort*)Wl + row * 72 + c8 * 8) =
            *(const uint4*)(base + idx * 8);                       // W
        *(uint4*)((ushort*)X2 + row * 144 + 72 + c8 * 8) =
            *(const uint4*)(base + 4096 + idx * 8);                // P
        *(uint4*)((ushort*)X2 + row * 144 + c8 * 8) =
            *(const uint4*)(base + 8192 + idx * 8);                // Qg
        *(uint4*)((ushort*)KsTl + row * 72 + c8 * 8) =
            *(const uint4*)(base + 12288 + idx * 8);               // KsT
        *(uint4*)((ushort*)Zl + row * 72 + c8 * 8) =
            *(const uint4*)(base + 16384 + row * 128 + H * 64 + c8 * 8);  // Z half
      }
      const int v = tid >> 2, ds = tid & 3;
#pragma unroll
      for (int e = 0; e < 16; ++e)
        Y2[v * 144 + ds * 16 + e] = (_Float16)Sf[v * 65 + ds * 16 + e];
    }
    __syncthreads();

    // b2: U = Z - W @ S0 -> Y2-right [bar]
    {
      f32x4 accU[2][2];
      gemm64(Wl, 72, Y2, 144, wr, wc, lane, 2, 0, accU);
#pragma unroll
      for (int m = 0; m < 2; ++m)
#pragma unroll
        for (int n = 0; n < 2; ++n)
#pragma unroll
          for (int j = 0; j < 4; ++j) {
            const int row = wr * 32 + m * 16 + (lane >> 4) * 4 + j;  // t
            const int col = wc * 32 + n * 16 + (lane & 15);          // v
            const float uval = (float)Zl[row * 72 + col] - accU[m][n][j];
            Y2[col * 144 + 72 + row] = (_Float16)uval;
          }
    }
    __syncthreads();

    // b3: S = egC*S + KsT@U ; O = [Qg|P]@[S0^T|U^T]^T -> o [bar]
    {
      f32x4 accS[2][2], accO[2][2];
      gemm64(KsTl, 72, Y2 + 72, 144, wr, wc, lane, 2, 0, accS);
      gemm64(X2, 144, Y2, 144, wr, wc, lane, 4, 8, accO);
#pragma unroll
      for (int m = 0; m < 2; ++m)
#pragma unroll
        for (int n = 0; n < 2; ++n)
#pragma unroll
          for (int j = 0; j < 4; ++j) {
            const int row = wr * 32 + m * 16 + (lane >> 4) * 4 + j;  // d (S) / t (O)
            const int col = wc * 32 + n * 16 + (lane & 15);          // v
            Sf[col * 65 + row] = egC * Sf[col * 65 + row] + accS[m][n][j];
            o[(((size_t)b * TT + c0 + row) * HH + h) * 128 + H * 64 + col] = accO[m][n][j];
          }
    }
    __syncthreads();
  }
}

// ---------------------------------------------------------------------------
// RMS norm over 128 + SiLU gate; emits fp16 for the final GEMM.
// ---------------------------------------------------------------------------
__global__ void rmsgate_kernel(const float* __restrict__ o, const float* __restrict__ gpre,
                               ushort* __restrict__ gof)
{
  int gid  = blockIdx.x * blockDim.x + threadIdx.x;
  int wid  = gid >> 6;
  int lane = threadIdx.x & 63;
  if (wid >= BB * TT * HH) return;
  int h = wid % HH;
  int m = wid / HH;
  const float* orow = o + (size_t)wid * 128;
  float2 ov = *(const float2*)(orow + lane * 2);
  float ss = ov.x * ov.x + ov.y * ov.y;
#pragma unroll
  for (int mm = 32; mm >= 1; mm >>= 1) ss += __shfl_xor(ss, mm, 64);
  float scale = rsqrtf(ss * (1.f / 128.f) + EPSF);
  const float* gr = gpre + (size_t)m * TVv + h * 128 + lane * 2;
  float o0 = ov.x * scale * siluf(gr[0]);
  float o1 = ov.y * scale * siluf(gr[1]);
  *(uint*)(gof + (size_t)m * TVv + h * 128 + lane * 2) = pk2h(o0, o1);
}

// ---------------------------------------------------------------------------
extern "C" void kernel_launch(void* const* d_in, const int* in_sizes, int n_in,
                              void* d_out, int out_size, void* d_ws, size_t ws_size,
                              hipStream_t stream) {
  (void)in_sizes; (void)n_in; (void)out_size; (void)ws_size;
  const float* x       = (const float*)d_in[0];
  const float* w_q     = (const float*)d_in[1];
  const float* w_k     = (const float*)d_in[2];
  const float* w_v     = (const float*)d_in[3];
  const float* w_a     = (const float*)d_in[4];
  const float* w_b     = (const float*)d_in[5];
  const float* w_g     = (const float*)d_in[6];
  const float* w_out   = (const float*)d_in[7];
  const float* A_log   = (const float*)d_in[8];
  const float* dt_bias = (const float*)d_in[9];
  const float* qcw     = (const float*)d_in[10];
  const float* kcw     = (const float*)d_in[11];
  const float* vcw     = (const float*)d_in[12];

  // Workspace (63.11 MB proven footprint), time-multiplexed:
  //  ws[0..6291456)        : qkv_pre (gemm->conv) -> SA scratch 18.9MB+egCg
  //                          (phaseA->phaseB) -> gof (rmsgate->final gemm)
  //  ws[6291456..9437184)  : g_pre
  //  ws[9437184..15728640) : Cu: xf+wcat -> qc/kc/vc -> o + woutf
  //  ws[15728640..15777792): abi
  float* ws      = (float*)d_ws;
  float* qkv_pre = ws;
  float* g_pre   = ws + 6291456;
  float* Cu      = ws + 9437184;
  float* abi     = ws + 15728640;

  ushort* xf    = (ushort*)Cu;
  ushort* wcat  = (ushort*)(Cu + 1572864);

  float* qc = Cu;
  float* kc = Cu + 1572864;
  float* vc = Cu + 3145728;

  _Float16* SA   = (_Float16*)ws;              // 384 units * 24576 f16
  float*    egCg = ws + 4718592;               // 384 floats

  float*  o     = Cu;                          // overwrites dead qc/kc
  ushort* woutf = (ushort*)(Cu + 3145728);     // overwrites dead vc
  ushort* gof   = (ushort*)ws;                 // overwrites dead SA scratch

  const int M = BB * TT;  // 2048
  dim3 blk(256);

  // 1) fp16 casts
  cast_f16_kernel<<<1536, blk, 0, stream>>>(x, xf);
  cast_w4_kernel<<<3456, blk, 0, stream>>>(w_q, w_k, w_v, w_g, wcat);

  // 2) fused qkv+g projection
  gemm_f16<<<dim3(NQKVG / 128, M / 128), blk, 0, stream>>>(
      xf, wcat, qkv_pre, g_pre, M, NQKVG, DD, CQKV, TVv, CQKV);

  // 3) gating coefficients
  gate_kernel<<<M, blk, 0, stream>>>(x, w_a, w_b, A_log, dt_bias, abi);

  // 4) conv + SiLU + L2 norm
  conv_silu_kernel<<<24576, blk, 0, stream>>>(qkv_pre, qcw, kcw, vcw, qc, kc, vc);

  // 5) scan: chunk-parallel phase A (full precompute), slim serial phase B
  scan_phaseA<<<16 * NBH, blk, 0, stream>>>(qc, kc, vc, abi, SA, egCg);
  scan_phaseB<<<2 * NBH, blk, 0, stream>>>(SA, egCg, o);

  // 6) cast w_out (into dead vc region)
  cast_f16_kernel<<<1152, blk, 0, stream>>>(w_out, woutf);

  // 7) RMS norm + SiLU gate (gof overwrites dead SA scratch)
  rmsgate_kernel<<<6144, blk, 0, stream>>>(o, g_pre, gof);

  // 8) output projection
  gemm_f16<<<dim3(TVv / 128, M / 128), blk, 0, stream>>>(
      gof, woutf, (float*)d_out, (float*)d_out, M, TVv, DD, TVv, TVv, TVv);
}